// Round 8
// baseline (348.437 us; speedup 1.0000x reference)
//
#include <hip/hip_runtime.h>
#include <hip/hip_cooperative_groups.h>
#include <cmath>

namespace cg = cooperative_groups;

#define BB 2
#define LL 2048
#define DD 1024
#define HH 16
#define HDD 64

typedef _Float16 v8h __attribute__((ext_vector_type(8)));
typedef _Float16 v4h __attribute__((ext_vector_type(4)));
typedef _Float16 v2h __attribute__((ext_vector_type(2)));
typedef float v4f __attribute__((ext_vector_type(4)));

#define LOG2E 1.44269504089f
#define NEGB  (-1.442695e9f)      /* -1e9 * log2e */

// async global->LDS, 16B per lane.
#define GLD(gp, lp)                                                        \
  __builtin_amdgcn_global_load_lds(                                        \
      (const __attribute__((address_space(1))) void*)(gp),                 \
      (__attribute__((address_space(3))) void*)(lp), 16, 0, 0)

// ---------------------------------------------------------------------------
// Fused prep: fp32->f16 cvt (hs, Wq/Wk/Wv, Wo) + cos/sin table + am*log2e
// + zero the per-row LN sum accumulators (re-zeroed every launch: the
// cooperative gemm_o_ln accumulates into them with atomics).
// ---------------------------------------------------------------------------
__global__ __launch_bounds__(256) void prep(
    const float* __restrict__ hs, const float* __restrict__ wq,
    const float* __restrict__ wk, const float* __restrict__ wv,
    const float* __restrict__ wo, const float* __restrict__ phi,
    const float* __restrict__ amk, _Float16* __restrict__ hsh,
    _Float16* __restrict__ wqkvh, _Float16* __restrict__ woh,
    unsigned* __restrict__ csh2, float* __restrict__ aml2,
    float* __restrict__ rsum, float* __restrict__ rsq)
{
  const int i = blockIdx.x * 256 + threadIdx.x;
  if (i < 2097152) {
    const float* s;
    _Float16* d;
    if (i < 1048576)      { s = hs + (size_t)i * 4;            d = hsh + (size_t)i * 4; }
    else if (i < 1310720) { int j = i - 1048576; s = wq + (size_t)j * 4; d = wqkvh + (size_t)j * 4; }
    else if (i < 1572864) { int j = i - 1310720; s = wk + (size_t)j * 4; d = wqkvh + 1048576 + (size_t)j * 4; }
    else if (i < 1835008) { int j = i - 1572864; s = wv + (size_t)j * 4; d = wqkvh + 2097152 + (size_t)j * 4; }
    else                  { int j = i - 1835008; s = wo + (size_t)j * 4; d = woh + (size_t)j * 4; }
    float4 v = *(const float4*)s;
    v4h o;
    o[0] = (_Float16)v.x; o[1] = (_Float16)v.y;
    o[2] = (_Float16)v.z; o[3] = (_Float16)v.w;
    *(v4h*)d = o;
  } else if (i < 2162688) {
    const int o = i - 2097152;                   // 0..65535 = B*H*L
    if (o < BB * LL) aml2[o] = amk[o] * LOG2E;
    const int l = o & 2047;
    const int h = (o >> 11) & 15;
    const int b = o >> 15;
    const float ph = phi[(b * 2048 + l) * 16 + h];
    v2h cs;
    cs[0] = (_Float16)cosf(ph);
    cs[1] = (_Float16)sinf(ph);
    csh2[o] = __builtin_bit_cast(unsigned, cs);
  } else {
    const int z = i - 2162688;                   // 0..4095 = rows
    rsum[z] = 0.f;
    rsq[z]  = 0.f;
  }
}

// ---------------------------------------------------------------------------
// m97-style MFMA GEMM core: 128x128 tile, BK=32, 256 thr.
// ---------------------------------------------------------------------------
__device__ __forceinline__ void gemm_loop(
    const _Float16* __restrict__ A, const _Float16* __restrict__ W, const int K,
    const int m0, const int n0, const int tid, const int wave, const int lane,
    _Float16* As, _Float16* Bs, v4f acc[4][4])
{
  const int quad = lane >> 4;
  const int ql = lane & 15;
  const int wm = (wave >> 1) * 64;
  const int wn = (wave & 1) * 64;
  const int srow = tid >> 2;
  const int skof = (tid & 3) * 8;
  const _Float16* Ap = A + (size_t)(m0 + srow) * K + skof;
  const _Float16* Wp = W + (size_t)(n0 + srow) * K + skof;
  const size_t rstep = (size_t)64 * K;
  for (int k0 = 0; k0 < K; k0 += 32) {
    __syncthreads();
    GLD(Ap + k0,         As + tid * 8);
    GLD(Ap + rstep + k0, As + 2048 + tid * 8);
    GLD(Wp + k0,         Bs + tid * 8);
    GLD(Wp + rstep + k0, Bs + 2048 + tid * 8);
    __syncthreads();
    v8h af[4], bf[4];
#pragma unroll
    for (int mt = 0; mt < 4; ++mt)
      af[mt] = *(const v8h*)&As[(wm + mt * 16 + ql) * 32 + quad * 8];
#pragma unroll
    for (int nt = 0; nt < 4; ++nt)
      bf[nt] = *(const v8h*)&Bs[(wn + nt * 16 + ql) * 32 + quad * 8];
#pragma unroll
    for (int mt = 0; mt < 4; ++mt)
#pragma unroll
      for (int nt = 0; nt < 4; ++nt)
        acc[mt][nt] = __builtin_amdgcn_mfma_f32_16x16x32_f16(
            af[mt], bf[nt], acc[mt][nt], 0, 0, 0);
  }
}

// ---------------------------------------------------------------------------
// Fused QKV GEMM (XCD-swizzled). Epilogue:
//   q-band: +bias, rotary (fp32), scale by (1/8)*log2e, single f16 rounding
//   k-band: +bias, rotary (fp32), f16
//   v-band: +bias, written directly in VT2 layout (8B unit [j=key>>2][d])
// ---------------------------------------------------------------------------
__global__ __launch_bounds__(256) void gemm_qkv(
    const _Float16* __restrict__ A, const _Float16* __restrict__ W,
    const float* __restrict__ bqp, const float* __restrict__ bkp,
    const float* __restrict__ bvp, const unsigned* __restrict__ csh2,
    _Float16* __restrict__ qh, _Float16* __restrict__ kh,
    _Float16* __restrict__ vt2)
{
  __shared__ _Float16 As[128 * 32];
  __shared__ _Float16 Bs[128 * 32];
  const int tid = threadIdx.x, lane = tid & 63, wave = tid >> 6;
  const int quad = lane >> 4, ql = lane & 15;
  const int bid0 = blockIdx.y * 24 + blockIdx.x;
  const int bid  = (bid0 & 7) * 96 + (bid0 >> 3);
  const int m0 = (bid / 24) * 128, n0 = (bid % 24) * 128;
  v4f acc[4][4];
#pragma unroll
  for (int mt = 0; mt < 4; ++mt)
#pragma unroll
    for (int nt = 0; nt < 4; ++nt) acc[mt][nt] = (v4f){0.f, 0.f, 0.f, 0.f};
  gemm_loop(A, W, DD, m0, n0, tid, wave, lane, As, Bs, acc);

  const int buf = n0 >> 10;                       // 0=q 1=k 2=v
  const int col0 = (n0 & 1023) + (wave & 1) * 64; // 64-col band == one head
  const int hh = col0 >> 6;
  const int mr0 = m0 + (wave >> 1) * 64;

  if (buf == 2) {
    float bb4[4];
#pragma unroll
    for (int nt = 0; nt < 4; ++nt) bb4[nt] = bvp[col0 + nt * 16 + ql];
#pragma unroll
    for (int mt = 0; mt < 4; ++mt) {
      const int row = mr0 + mt * 16 + quad * 4;   // keys row..row+3
      const int b_ = row >> 11;
      const int l = row & 2047;
      _Float16* dst = vt2 + ((size_t)(b_ * 16 + hh) * 32 + (l >> 6)) * 4096 +
                      ((l >> 2) & 15) * 256;
#pragma unroll
      for (int nt = 0; nt < 4; ++nt) {
        const int d = nt * 16 + ql;
        v4h o4;
#pragma unroll
        for (int r = 0; r < 4; ++r) o4[r] = (_Float16)(acc[mt][nt][r] + bb4[nt]);
        *(v4h*)&dst[d * 4] = o4;
      }
    }
  } else {
    const float scl = (buf == 0) ? 0.125f * LOG2E : 1.0f;
    _Float16* outp = (buf == 0) ? qh : kh;
    const float* bias = (buf == 0) ? bqp : bkp;
    float bb4[4];
#pragma unroll
    for (int nt = 0; nt < 4; ++nt) bb4[nt] = bias[col0 + nt * 16 + ql];
#pragma unroll
    for (int mt = 0; mt < 4; ++mt)
#pragma unroll
      for (int r = 0; r < 4; ++r) {
        const int row = mr0 + mt * 16 + quad * 4 + r;
        const int b_ = row >> 11;
        const int l = row & 2047;
        const v2h c2 = __builtin_bit_cast(
            v2h, csh2[(b_ * 16 + hh) * 2048 + l]);
        const float c = (float)c2[0], s = (float)c2[1];
        _Float16* orow = outp + (size_t)row * DD + col0 + ql;
#pragma unroll
        for (int pp = 0; pp < 2; ++pp) {
          const float a0 = acc[mt][pp][r] + bb4[pp];
          const float a1 = acc[mt][pp + 2][r] + bb4[pp + 2];
          orow[pp * 16]        = (_Float16)((a0 * c - a1 * s) * scl);
          orow[(pp + 2) * 16]  = (_Float16)((a1 * c + a0 * s) * scl);
        }
      }
  }
}

// ---------------------------------------------------------------------------
// COOPERATIVE O-proj GEMM + residual + LayerNorm, fused. 512 blocks at
// 2/CU co-resident (launch_bounds(256,2), LDS 12KB). Eliminates the 32MB
// fp32 intermediate write + 32MB read + the separate LN kernel.
// Phase 1: tile vals = acc + bias + residual (held in registers); per-row
//   partial sum/sumsq reduced across 16-lane groups, atomicAdd (device
//   scope) into rsum/rsq[4096].
// threadfence + grid.sync()
// Phase 2: load complete row sums with device-scope atomic loads (cross-XCD
//   safe, bypasses L1), normalize register vals, write final output.
// ---------------------------------------------------------------------------
__global__ __launch_bounds__(256, 2) void gemm_o_ln(
    const _Float16* __restrict__ A, const _Float16* __restrict__ W,
    const float* __restrict__ bo, const float* __restrict__ res,
    const float* __restrict__ g, const float* __restrict__ bta,
    float* __restrict__ rsum, float* __restrict__ rsq,
    float* __restrict__ out)
{
  __shared__ _Float16 As[128 * 32];
  __shared__ _Float16 Bs[64 * 32];
  const int tid = threadIdx.x, lane = tid & 63, wave = tid >> 6;
  const int quad = lane >> 4, ql = lane & 15;
  const int bid0 = blockIdx.y * 16 + blockIdx.x;
  const int bid  = (bid0 & 7) * 64 + (bid0 >> 3);   // XCD swizzle
  const int m0 = (bid / 16) * 128, n0 = (bid % 16) * 64;
  v4f acc[4][2];
#pragma unroll
  for (int mt = 0; mt < 4; ++mt)
#pragma unroll
    for (int nt = 0; nt < 2; ++nt) acc[mt][nt] = (v4f){0.f, 0.f, 0.f, 0.f};
  const int wm = (wave >> 1) * 64;
  const int wn = (wave & 1) * 32;
  const int srow = tid >> 2;
  const int skof = (tid & 3) * 8;
  const _Float16* Ap = A + (size_t)(m0 + srow) * DD + skof;
  const _Float16* Wp = W + (size_t)(n0 + srow) * DD + skof;
  const size_t rstep = (size_t)64 * DD;
  for (int k0 = 0; k0 < DD; k0 += 32) {
    __syncthreads();
    GLD(Ap + k0,         As + tid * 8);
    GLD(Ap + rstep + k0, As + 2048 + tid * 8);
    GLD(Wp + k0,         Bs + tid * 8);
    __syncthreads();
    v8h af[4], bf[2];
#pragma unroll
    for (int mt = 0; mt < 4; ++mt)
      af[mt] = *(const v8h*)&As[(wm + mt * 16 + ql) * 32 + quad * 8];
#pragma unroll
    for (int nt = 0; nt < 2; ++nt)
      bf[nt] = *(const v8h*)&Bs[(wn + nt * 16 + ql) * 32 + quad * 8];
#pragma unroll
    for (int mt = 0; mt < 4; ++mt)
#pragma unroll
      for (int nt = 0; nt < 2; ++nt)
        acc[mt][nt] = __builtin_amdgcn_mfma_f32_16x16x32_f16(
            af[mt], bf[nt], acc[mt][nt], 0, 0, 0);
  }

  // --- phase 1: vals (in acc) = acc + bias + residual; row partial sums ---
  float bb[2];
#pragma unroll
  for (int nt = 0; nt < 2; ++nt) bb[nt] = bo[n0 + wn + nt * 16 + ql];
#pragma unroll
  for (int mt = 0; mt < 4; ++mt)
#pragma unroll
    for (int r = 0; r < 4; ++r) {
      const int row = m0 + wm + mt * 16 + quad * 4 + r;
#pragma unroll
      for (int nt = 0; nt < 2; ++nt) {
        const int col = n0 + wn + nt * 16 + ql;
        acc[mt][nt][r] += bb[nt] + res[(size_t)row * DD + col];
      }
    }
#pragma unroll
  for (int mt = 0; mt < 4; ++mt)
#pragma unroll
    for (int r = 0; r < 4; ++r) {
      const float a = acc[mt][0][r], b = acc[mt][1][r];
      float s = a + b;
      float q2 = a * a + b * b;
#pragma unroll
      for (int off = 1; off < 16; off <<= 1) {
        s  += __shfl_xor(s,  off, 64);
        q2 += __shfl_xor(q2, off, 64);
      }
      if (ql == 0) {
        const int row = m0 + wm + mt * 16 + quad * 4 + r;
        atomicAdd(&rsum[row], s);
        atomicAdd(&rsq[row],  q2);
      }
    }
  __threadfence();
  cg::this_grid().sync();

  // --- phase 2: normalize register vals with complete row stats ---
#pragma unroll
  for (int mt = 0; mt < 4; ++mt)
#pragma unroll
    for (int r = 0; r < 4; ++r) {
      const int row = m0 + wm + mt * 16 + quad * 4 + r;
      const float ts = __hip_atomic_load(&rsum[row], __ATOMIC_RELAXED,
                                         __HIP_MEMORY_SCOPE_AGENT);
      const float tq = __hip_atomic_load(&rsq[row], __ATOMIC_RELAXED,
                                         __HIP_MEMORY_SCOPE_AGENT);
      const float mean = ts * (1.f / DD);
      const float var  = tq * (1.f / DD) - mean * mean;
      const float inv  = rsqrtf(var + 1e-12f);
#pragma unroll
      for (int nt = 0; nt < 2; ++nt) {
        const int col = n0 + wn + nt * 16 + ql;
        out[(size_t)row * DD + col] =
            (acc[mt][nt][r] - mean) * inv * g[col] + bta[col];
      }
    }
}

// ---------------------------------------------------------------------------
// Double-buffered LDS flash attention (R7 structure, session best: 32 q/wave,
// two 16-q groups, 2 blocks/CU, setprio around PV, t-loop unrolled x2 for
// compile-time LDS buffer index).
// ---------------------------------------------------------------------------
__global__ __launch_bounds__(256, 2) void attn_db(
    const _Float16* __restrict__ Q, const _Float16* __restrict__ K,
    const _Float16* __restrict__ VT2, const unsigned* __restrict__ csh2,
    const float* __restrict__ aml2, _Float16* __restrict__ ctx)
{
  __shared__ _Float16 Kt[2][4096];   // [buf] 64 rows x 64 dims (16B-swizzled)
  __shared__ _Float16 Vt[2][4096];   // [buf] VT2 tile image (8B units j-major)
  __shared__ float amL[LL];          // am * log2e, whole row: 8 KB

  const int tid  = threadIdx.x;
  const int lane = tid & 63;
  const int wave = tid >> 6;
  const int quad = lane >> 4;
  const int ql   = lane & 15;
  const int bid  = blockIdx.x;       // 512 = 16 qt * 32 bh
  const int bh = bid & 31;           // XCD swizzle: same (b,h) -> same XCD
  const int qt = bid >> 5;
  const int h  = bh & 15;
  const int b  = bh >> 4;
  const int q0w = qt * 128 + wave * 32;   // 32 queries per wave
  const int csb = bh * LL;

  {
    const float* amb = aml2 + b * LL;
    for (int i = tid; i < LL; i += 256) amL[i] = amb[i];
  }

  // Q B-fragments for the two 16-query groups (rotary etc. pre-folded)
  v8h qf0[2], qf1[2];
  v4h bq0, bq1;
  {
    const _Float16* qp = Q + ((size_t)(b * LL + q0w + ql)) * DD + h * 64 + quad * 8;
    qf0[0] = *(const v8h*)qp;
    qf0[1] = *(const v8h*)(qp + 32);
    const v2h c2 = __builtin_bit_cast(v2h, csh2[csb + q0w + ql]);
    v4h t = (v4h){0, 0, 0, 0};
    if (quad == 0) { t[0] = c2[0]; t[1] = c2[1]; }
    bq0 = t;
  }
  {
    const _Float16* qp = Q + ((size_t)(b * LL + q0w + 16 + ql)) * DD + h * 64 + quad * 8;
    qf1[0] = *(const v8h*)qp;
    qf1[1] = *(const v8h*)(qp + 32);
    const v2h c2 = __builtin_bit_cast(v2h, csh2[csb + q0w + 16 + ql]);
    v4h t = (v4h){0, 0, 0, 0};
    if (quad == 0) { t[0] = c2[0]; t[1] = c2[1]; }
    bq1 = t;
  }
  const v4h ones = (v4h){(_Float16)1.f, (_Float16)1.f,
                         (_Float16)1.f, (_Float16)1.f};

  v4f o0[4], o1[4];
#pragma unroll
  for (int nt = 0; nt < 4; ++nt) {
    o0[nt] = (v4f){0.f, 0.f, 0.f, 0.f};
    o1[nt] = (v4f){0.f, 0.f, 0.f, 0.f};
  }
  v4f lacc0 = (v4f){0.f, 0.f, 0.f, 0.f};
  v4f lacc1 = (v4f){0.f, 0.f, 0.f, 0.f};

  const _Float16* Kb   = K + (size_t)(b * LL) * DD + h * 64;     // row stride 1024
  const _Float16* VTb2 = VT2 + (size_t)bh * 131072;              // 32 tiles x 4096
  const unsigned* csk = csh2 + csb;

  const int srow = tid >> 3;                // 0..31 K staging row
  const int kch  = (tid & 7) ^ (srow & 7);  // swizzled source 16B chunk (K only)

  // prologue: tile 0 -> buf 0; csk for tile 0 -> registers
  {
    const size_t kg = (size_t)srow * 1024 + kch * 8;
    GLD(Kb + kg,             &Kt[0][tid * 8]);
    GLD(Kb + kg + 32 * 1024, &Kt[0][2048 + tid * 8]);
    GLD(VTb2 + tid * 8,          &Vt[0][tid * 8]);
    GLD(VTb2 + 2048 + tid * 8,   &Vt[0][2048 + tid * 8]);
  }
  unsigned cs_cur[4], cs_nxt[4];
#pragma unroll
  for (int c = 0; c < 4; ++c) cs_cur[c] = csk[c * 16 + ql];
  __syncthreads();

  for (int tt = 0; tt < 16; ++tt) {
#pragma unroll
    for (int u = 0; u < 2; ++u) {          // u == compile-time buffer index
      const int t = tt * 2 + u;
      const int k0 = t * 64;
      if (t < 31) {
        const int k1 = k0 + 64;
        const size_t kg = (size_t)(k1 + srow) * 1024 + kch * 8;
        GLD(Kb + kg,             &Kt[u ^ 1][tid * 8]);
        GLD(Kb + kg + 32 * 1024, &Kt[u ^ 1][2048 + tid * 8]);
        const _Float16* vsrc = VTb2 + (size_t)(t + 1) * 4096;
        GLD(vsrc + tid * 8,        &Vt[u ^ 1][tid * 8]);
        GLD(vsrc + 2048 + tid * 8, &Vt[u ^ 1][2048 + tid * 8]);
#pragma unroll
        for (int c = 0; c < 4; ++c) cs_nxt[c] = csk[k1 + c * 16 + ql];
      }
      const _Float16* KtB = Kt[u];
      const _Float16* VtB = Vt[u];

      // --- S^T (log2 domain) + mask-dot MFMA, q-groups sharing K frags ---
      v4f st0[4], st1[4], dd0[4], dd1[4];
#pragma unroll
      for (int c = 0; c < 4; ++c) {
        const int row = c * 16 + ql;
        const int sw = row & 7;
        v8h a0 = *(const v8h*)&KtB[row * 64 + ((quad ^ sw) << 3)];
        v8h a1 = *(const v8h*)&KtB[row * 64 + (((quad + 4) ^ sw) << 3)];
        v4f z0 = (v4f){0.f, 0.f, 0.f, 0.f};
        z0 = __builtin_amdgcn_mfma_f32_16x16x32_f16(a0, qf0[0], z0, 0, 0, 0);
        z0 = __builtin_amdgcn_mfma_f32_16x16x32_f16(a1, qf0[1], z0, 0, 0, 0);
        st0[c] = z0;
        v4f z1 = (v4f){0.f, 0.f, 0.f, 0.f};
        z1 = __builtin_amdgcn_mfma_f32_16x16x32_f16(a0, qf1[0], z1, 0, 0, 0);
        z1 = __builtin_amdgcn_mfma_f32_16x16x32_f16(a1, qf1[1], z1, 0, 0, 0);
        st1[c] = z1;
        const v2h c2 = __builtin_bit_cast(v2h, cs_cur[c]);
        v4h a = (v4h){0, 0, 0, 0};
        if (quad == 0) { a[0] = c2[0]; a[1] = c2[1]; }
        dd0[c] = __builtin_amdgcn_mfma_f32_16x16x16f16(
            a, bq0, (v4f){0.f, 0.f, 0.f, 0.f}, 0, 0, 0);
        dd1[c] = __builtin_amdgcn_mfma_f32_16x16x16f16(
            a, bq1, (v4f){0.f, 0.f, 0.f, 0.f}, 0, 0, 0);
      }

      // --- mask + P = exp2(score + am): cmp + cndmask + add + exp2 ---
      v4h pf0[4], pf1[4];
#pragma unroll
      for (int c = 0; c < 4; ++c) {
        const v4f am4 = *(const v4f*)&amL[k0 + c * 16 + quad * 4];
        float p0[4], p1[4];
#pragma unroll
        for (int r = 0; r < 4; ++r) {
          p0[r] = __builtin_amdgcn_exp2f(
              ((dd0[c][r] < -0.7f) ? NEGB : st0[c][r]) + am4[r]);
          p1[r] = __builtin_amdgcn_exp2f(
              ((dd1[c][r] < -0.7f) ? NEGB : st1[c][r]) + am4[r]);
        }
        const unsigned a01 = __builtin_bit_cast(
            unsigned, __builtin_amdgcn_cvt_pkrtz(p0[0], p0[1]));
        const unsigned a23 = __builtin_bit_cast(
            unsigned, __builtin_amdgcn_cvt_pkrtz(p0[2], p0[3]));
        pf0[c] = __builtin_bit_cast(v4h, make_uint2(a01, a23));
        const unsigned b01 = __builtin_bit_cast(
            unsigned, __builtin_amdgcn_cvt_pkrtz(p1[0], p1[1]));
        const unsigned b23 = __builtin_bit_cast(
            unsigned, __builtin_amdgcn_cvt_pkrtz(p1[2], p1[3]));
        pf1[c] = __builtin_bit_cast(v4h, make_uint2(b01, b23));
      }

      // --- PV + row-sum, V frags shared by both q-groups (pure MFMA) ---
      __builtin_amdgcn_s_setprio(1);
#pragma unroll
      for (int c = 0; c < 4; ++c) {
        lacc0 = __builtin_amdgcn_mfma_f32_16x16x16f16(pf0[c], ones, lacc0, 0, 0, 0);
        lacc1 = __builtin_amdgcn_mfma_f32_16x16x16f16(pf1[c], ones, lacc1, 0, 0, 0);
#pragma unroll
        for (int nt = 0; nt < 4; ++nt) {
          const v4h vv = *(const v4h*)&VtB[((c * 4 + quad) * 64 +
                                            nt * 16 + ql) * 4];
          o0[nt] = __builtin_amdgcn_mfma_f32_16x16x16f16(pf0[c], vv, o0[nt], 0, 0, 0);
          o1[nt] = __builtin_amdgcn_mfma_f32_16x16x16f16(pf1[c], vv, o1[nt], 0, 0, 0);
        }
      }
      __builtin_amdgcn_s_setprio(0);
#pragma unroll
      for (int c = 0; c < 4; ++c) cs_cur[c] = cs_nxt[c];
      __syncthreads();
    }
  }

  // epilogue: lacc is already in O's row layout (query = g*16 + quad*4 + r)
#pragma unroll
  for (int g = 0; g < 2; ++g) {
    const v4f* op = g ? o1 : o0;
    const v4f la = g ? lacc1 : lacc0;
#pragma unroll
    for (int r = 0; r < 4; ++r) {
      const int q = q0w + g * 16 + quad * 4 + r;
      const float lr = la[r];
      const size_t ob = (size_t)(b * LL + q) * DD + h * 64 + ql;
      if (lr <= 0.f) {  // all-masked fallback (never taken with am=0)
        const _Float16* vsrc = VTb2 + (q >> 6) * 4096 +
                               ((q >> 2) & 15) * 256 + (q & 3);
#pragma unroll
        for (int nt = 0; nt < 4; ++nt)
          ctx[ob + nt * 16] = vsrc[(nt * 16 + ql) * 4];
      } else {
        const float inv = 1.f / lr;
        ctx[ob + 0]  = (_Float16)(op[0][r] * inv);
        ctx[ob + 16] = (_Float16)(op[1][r] * inv);
        ctx[ob + 32] = (_Float16)(op[2][r] * inv);
        ctx[ob + 48] = (_Float16)(op[3][r] * inv);
      }
    }
  }
}

// ---------------------------------------------------------------------------
extern "C" void kernel_launch(void* const* d_in, const int* in_sizes, int n_in,
                              void* d_out, int out_size, void* d_ws, size_t ws_size,
                              hipStream_t stream)
{
  const float* hs  = (const float*)d_in[0];
  const float* amk = (const float*)d_in[1];
  const float* phi = (const float*)d_in[2];
  const float* Wq  = (const float*)d_in[3];
  const float* bq  = (const float*)d_in[4];
  const float* Wk  = (const float*)d_in[5];
  const float* bk  = (const float*)d_in[6];
  const float* Wv  = (const float*)d_in[7];
  const float* bv  = (const float*)d_in[8];
  const float* Wo  = (const float*)d_in[9];
  const float* bo  = (const float*)d_in[10];
  const float* lng = (const float*)d_in[11];
  const float* lnb = (const float*)d_in[12];
  float* out = (float*)d_out;

  const size_t SZ = (size_t)BB * LL * DD;   // 4 M elements
  _Float16* hsh   = (_Float16*)d_ws;
  _Float16* qh    = hsh + SZ;
  _Float16* kh    = qh + SZ;
  _Float16* vt2   = kh + SZ;                // 4 M (V pre-tiled VT2)
  _Float16* ctxh  = vt2 + SZ;
  _Float16* wqkvh = ctxh + SZ;              // 3 M
  _Float16* woh   = wqkvh + 3 * (size_t)DD * DD;  // 1 M
  unsigned* csh2 = (unsigned*)(woh + (size_t)DD * DD);  // B*H*L packed {cos,sin}
  float* aml2 = (float*)(csh2 + (size_t)BB * HH * LL);  // B*L am*log2e
  float* rsum = aml2 + (size_t)BB * LL;     // per-row LN sums [B*L]
  float* rsq  = rsum + (size_t)BB * LL;

  prep<<<8464, 256, 0, stream>>>(hs, Wq, Wk, Wv, Wo, phi, amk,
                                 hsh, wqkvh, woh, csh2, aml2, rsum, rsq);
  gemm_qkv<<<dim3(24, 32), 256, 0, stream>>>(hsh, wqkvh, bq, bk, bv, csh2,
                                             qh, kh, vt2);
  attn_db<<<512, 256, 0, stream>>>(qh, kh, vt2, csh2, aml2, ctxh);
  {
    const _Float16* a_ = ctxh;
    const _Float16* w_ = woh;
    void* args[] = {(void*)&a_, (void*)&w_, (void*)&bo, (void*)&hs,
                    (void*)&lng, (void*)&lnb, (void*)&rsum, (void*)&rsq,
                    (void*)&out};
    hipLaunchCooperativeKernel((void*)gemm_o_ln, dim3(16, 32), dim3(256),
                               args, 0, stream);
  }
}

// Round 9
// 298.903 us; speedup vs baseline: 1.1657x; 1.1657x over previous
//
#include <hip/hip_runtime.h>
#include <cmath>

#define BB 2
#define LL 2048
#define DD 1024
#define HH 16
#define HDD 64

typedef _Float16 v8h __attribute__((ext_vector_type(8)));
typedef _Float16 v4h __attribute__((ext_vector_type(4)));
typedef _Float16 v2h __attribute__((ext_vector_type(2)));
typedef float v4f __attribute__((ext_vector_type(4)));

#define LOG2E 1.44269504089f
#define NEGB  (-1.442695e9f)      /* -1e9 * log2e */

// async global->LDS, 16B per lane.
#define GLD(gp, lp)                                                        \
  __builtin_amdgcn_global_load_lds(                                        \
      (const __attribute__((address_space(1))) void*)(gp),                 \
      (__attribute__((address_space(3))) void*)(lp), 16, 0, 0)

// ---------------------------------------------------------------------------
// Fused prep: fp32->f16 cvt (hs, Wq/Wk/Wv, Wo) + cos/sin table + am*log2e.
// ---------------------------------------------------------------------------
__global__ __launch_bounds__(256) void prep(
    const float* __restrict__ hs, const float* __restrict__ wq,
    const float* __restrict__ wk, const float* __restrict__ wv,
    const float* __restrict__ wo, const float* __restrict__ phi,
    const float* __restrict__ amk, _Float16* __restrict__ hsh,
    _Float16* __restrict__ wqkvh, _Float16* __restrict__ woh,
    unsigned* __restrict__ csh2, float* __restrict__ aml2)
{
  const int i = blockIdx.x * 256 + threadIdx.x;
  if (i < 2097152) {
    const float* s;
    _Float16* d;
    if (i < 1048576)      { s = hs + (size_t)i * 4;            d = hsh + (size_t)i * 4; }
    else if (i < 1310720) { int j = i - 1048576; s = wq + (size_t)j * 4; d = wqkvh + (size_t)j * 4; }
    else if (i < 1572864) { int j = i - 1310720; s = wk + (size_t)j * 4; d = wqkvh + 1048576 + (size_t)j * 4; }
    else if (i < 1835008) { int j = i - 1572864; s = wv + (size_t)j * 4; d = wqkvh + 2097152 + (size_t)j * 4; }
    else                  { int j = i - 1835008; s = wo + (size_t)j * 4; d = woh + (size_t)j * 4; }
    float4 v = *(const float4*)s;
    v4h o;
    o[0] = (_Float16)v.x; o[1] = (_Float16)v.y;
    o[2] = (_Float16)v.z; o[3] = (_Float16)v.w;
    *(v4h*)d = o;
  } else {
    const int o = i - 2097152;                   // 0..65535 = B*H*L
    if (o < BB * LL) aml2[o] = amk[o] * LOG2E;
    const int l = o & 2047;
    const int h = (o >> 11) & 15;
    const int b = o >> 15;
    const float ph = phi[(b * 2048 + l) * 16 + h];
    v2h cs;
    cs[0] = (_Float16)cosf(ph);
    cs[1] = (_Float16)sinf(ph);
    csh2[o] = __builtin_bit_cast(unsigned, cs);
  }
}

// ---------------------------------------------------------------------------
// m97-style MFMA GEMM core: 128x128 tile, BK=32, 256 thr.
// ---------------------------------------------------------------------------
__device__ __forceinline__ void gemm_loop(
    const _Float16* __restrict__ A, const _Float16* __restrict__ W, const int K,
    const int m0, const int n0, const int tid, const int wave, const int lane,
    _Float16* As, _Float16* Bs, v4f acc[4][4])
{
  const int quad = lane >> 4;
  const int ql = lane & 15;
  const int wm = (wave >> 1) * 64;
  const int wn = (wave & 1) * 64;
  const int srow = tid >> 2;
  const int skof = (tid & 3) * 8;
  const _Float16* Ap = A + (size_t)(m0 + srow) * K + skof;
  const _Float16* Wp = W + (size_t)(n0 + srow) * K + skof;
  const size_t rstep = (size_t)64 * K;
  for (int k0 = 0; k0 < K; k0 += 32) {
    __syncthreads();
    GLD(Ap + k0,         As + tid * 8);
    GLD(Ap + rstep + k0, As + 2048 + tid * 8);
    GLD(Wp + k0,         Bs + tid * 8);
    GLD(Wp + rstep + k0, Bs + 2048 + tid * 8);
    __syncthreads();
    v8h af[4], bf[4];
#pragma unroll
    for (int mt = 0; mt < 4; ++mt)
      af[mt] = *(const v8h*)&As[(wm + mt * 16 + ql) * 32 + quad * 8];
#pragma unroll
    for (int nt = 0; nt < 4; ++nt)
      bf[nt] = *(const v8h*)&Bs[(wn + nt * 16 + ql) * 32 + quad * 8];
#pragma unroll
    for (int mt = 0; mt < 4; ++mt)
#pragma unroll
      for (int nt = 0; nt < 4; ++nt)
        acc[mt][nt] = __builtin_amdgcn_mfma_f32_16x16x32_f16(
            af[mt], bf[nt], acc[mt][nt], 0, 0, 0);
  }
}

// ---------------------------------------------------------------------------
// Fused QKV GEMM (XCD-swizzled). Epilogue:
//   q-band: +bias, rotary (fp32), scale by (1/8)*log2e, single f16 rounding
//   k-band: +bias, rotary (fp32), f16
//   v-band: +bias, written directly in VT2 layout (8B unit [j=key>>2][d])
// ---------------------------------------------------------------------------
__global__ __launch_bounds__(256) void gemm_qkv(
    const _Float16* __restrict__ A, const _Float16* __restrict__ W,
    const float* __restrict__ bqp, const float* __restrict__ bkp,
    const float* __restrict__ bvp, const unsigned* __restrict__ csh2,
    _Float16* __restrict__ qh, _Float16* __restrict__ kh,
    _Float16* __restrict__ vt2)
{
  __shared__ _Float16 As[128 * 32];
  __shared__ _Float16 Bs[128 * 32];
  const int tid = threadIdx.x, lane = tid & 63, wave = tid >> 6;
  const int quad = lane >> 4, ql = lane & 15;
  const int bid0 = blockIdx.y * 24 + blockIdx.x;
  const int bid  = (bid0 & 7) * 96 + (bid0 >> 3);
  const int m0 = (bid / 24) * 128, n0 = (bid % 24) * 128;
  v4f acc[4][4];
#pragma unroll
  for (int mt = 0; mt < 4; ++mt)
#pragma unroll
    for (int nt = 0; nt < 4; ++nt) acc[mt][nt] = (v4f){0.f, 0.f, 0.f, 0.f};
  gemm_loop(A, W, DD, m0, n0, tid, wave, lane, As, Bs, acc);

  const int buf = n0 >> 10;                       // 0=q 1=k 2=v
  const int col0 = (n0 & 1023) + (wave & 1) * 64; // 64-col band == one head
  const int hh = col0 >> 6;
  const int mr0 = m0 + (wave >> 1) * 64;

  if (buf == 2) {
    float bb4[4];
#pragma unroll
    for (int nt = 0; nt < 4; ++nt) bb4[nt] = bvp[col0 + nt * 16 + ql];
#pragma unroll
    for (int mt = 0; mt < 4; ++mt) {
      const int row = mr0 + mt * 16 + quad * 4;   // keys row..row+3
      const int b_ = row >> 11;
      const int l = row & 2047;
      _Float16* dst = vt2 + ((size_t)(b_ * 16 + hh) * 32 + (l >> 6)) * 4096 +
                      ((l >> 2) & 15) * 256;
#pragma unroll
      for (int nt = 0; nt < 4; ++nt) {
        const int d = nt * 16 + ql;
        v4h o4;
#pragma unroll
        for (int r = 0; r < 4; ++r) o4[r] = (_Float16)(acc[mt][nt][r] + bb4[nt]);
        *(v4h*)&dst[d * 4] = o4;
      }
    }
  } else {
    const float scl = (buf == 0) ? 0.125f * LOG2E : 1.0f;
    _Float16* outp = (buf == 0) ? qh : kh;
    const float* bias = (buf == 0) ? bqp : bkp;
    float bb4[4];
#pragma unroll
    for (int nt = 0; nt < 4; ++nt) bb4[nt] = bias[col0 + nt * 16 + ql];
#pragma unroll
    for (int mt = 0; mt < 4; ++mt)
#pragma unroll
      for (int r = 0; r < 4; ++r) {
        const int row = mr0 + mt * 16 + quad * 4 + r;
        const int b_ = row >> 11;
        const int l = row & 2047;
        const v2h c2 = __builtin_bit_cast(
            v2h, csh2[(b_ * 16 + hh) * 2048 + l]);
        const float c = (float)c2[0], s = (float)c2[1];
        _Float16* orow = outp + (size_t)row * DD + col0 + ql;
#pragma unroll
        for (int pp = 0; pp < 2; ++pp) {
          const float a0 = acc[mt][pp][r] + bb4[pp];
          const float a1 = acc[mt][pp + 2][r] + bb4[pp + 2];
          orow[pp * 16]        = (_Float16)((a0 * c - a1 * s) * scl);
          orow[(pp + 2) * 16]  = (_Float16)((a1 * c + a0 * s) * scl);
        }
      }
  }
}

// ---------------------------------------------------------------------------
// O-proj GEMM, 128(M)x64(N) tiles: 512 blocks (2/CU), XCD-swizzled.
// ---------------------------------------------------------------------------
__global__ __launch_bounds__(256) void gemm_o(
    const _Float16* __restrict__ A, const _Float16* __restrict__ W,
    const float* __restrict__ bo, const float* __restrict__ res,
    float* __restrict__ out)
{
  __shared__ _Float16 As[128 * 32];
  __shared__ _Float16 Bs[64 * 32];
  const int tid = threadIdx.x, lane = tid & 63, wave = tid >> 6;
  const int quad = lane >> 4, ql = lane & 15;
  const int bid0 = blockIdx.y * 16 + blockIdx.x;
  const int bid  = (bid0 & 7) * 64 + (bid0 >> 3);
  const int m0 = (bid / 16) * 128, n0 = (bid % 16) * 64;
  v4f acc[4][2];
#pragma unroll
  for (int mt = 0; mt < 4; ++mt)
#pragma unroll
    for (int nt = 0; nt < 2; ++nt) acc[mt][nt] = (v4f){0.f, 0.f, 0.f, 0.f};
  const int wm = (wave >> 1) * 64;
  const int wn = (wave & 1) * 32;
  const int srow = tid >> 2;
  const int skof = (tid & 3) * 8;
  const _Float16* Ap = A + (size_t)(m0 + srow) * DD + skof;
  const _Float16* Wp = W + (size_t)(n0 + srow) * DD + skof;
  const size_t rstep = (size_t)64 * DD;
  for (int k0 = 0; k0 < DD; k0 += 32) {
    __syncthreads();
    GLD(Ap + k0,         As + tid * 8);
    GLD(Ap + rstep + k0, As + 2048 + tid * 8);
    GLD(Wp + k0,         Bs + tid * 8);
    __syncthreads();
    v8h af[4], bf[2];
#pragma unroll
    for (int mt = 0; mt < 4; ++mt)
      af[mt] = *(const v8h*)&As[(wm + mt * 16 + ql) * 32 + quad * 8];
#pragma unroll
    for (int nt = 0; nt < 2; ++nt)
      bf[nt] = *(const v8h*)&Bs[(wn + nt * 16 + ql) * 32 + quad * 8];
#pragma unroll
    for (int mt = 0; mt < 4; ++mt)
#pragma unroll
      for (int nt = 0; nt < 2; ++nt)
        acc[mt][nt] = __builtin_amdgcn_mfma_f32_16x16x32_f16(
            af[mt], bf[nt], acc[mt][nt], 0, 0, 0);
  }
#pragma unroll
  for (int nt = 0; nt < 2; ++nt) {
    const int col = n0 + wn + nt * 16 + ql;
    const float bb = bo[col];
#pragma unroll
    for (int mt = 0; mt < 4; ++mt)
#pragma unroll
      for (int r = 0; r < 4; ++r) {
        const int row = m0 + wm + mt * 16 + quad * 4 + r;
        const size_t ix = (size_t)row * DD + col;
        out[ix] = acc[mt][nt][r] + bb + res[ix];
      }
  }
}

// ---------------------------------------------------------------------------
// K-SPLIT flash attention. Wave count at 32q/wave was capped at 2048 waves
// (2/SIMD) -- the measured ~45% dependency stall could not be hidden. Split
// the KEY range instead: wave pairs (even=keys 0..1023, odd=1024..2047)
// cover the SAME 32 queries; partial o/l sums combine EXACTLY (no online
// max -- softmax here is a pure sum) via one LDS exchange at the end.
// 512-thr blocks: 4 pairs x 32q = 128 q/block, grid 512, 2 blocks/CU
// -> 16 waves/CU = 4/SIMD (2x TLP at identical per-wave work).
// LDS: Kt[2 halves][2 buf] + Vt same (64KB) + amL (8KB) = 72KB.
// 16 steps/wave (half the barriers of R7). setprio kept around PV.
// ---------------------------------------------------------------------------
__global__ __launch_bounds__(512, 4) void attn_db(
    const _Float16* __restrict__ Q, const _Float16* __restrict__ K,
    const _Float16* __restrict__ VT2, const unsigned* __restrict__ csh2,
    const float* __restrict__ aml2, _Float16* __restrict__ ctx)
{
  __shared__ _Float16 Kt[2][2][4096];   // [khalf][buf] 64 rows x 64 dims
  __shared__ _Float16 Vt[2][2][4096];   // [khalf][buf] VT2 tile image
  __shared__ float amL[LL];             // am * log2e: 8 KB

  const int tid  = threadIdx.x;         // 0..511
  const int lane = tid & 63;
  const int wave = tid >> 6;            // 0..7
  const int quad = lane >> 4;
  const int ql   = lane & 15;
  const int bid  = blockIdx.x;          // 512 = 16 qt * 32 bh
  const int bh = bid & 31;              // XCD swizzle: same (b,h) -> same XCD
  const int qt = bid >> 5;
  const int h  = bh & 15;
  const int b  = bh >> 4;
  const int pair = wave >> 1;           // 0..3: which 32-query slice
  const int kh2  = wave & 1;            // 0: keys 0..1023, 1: keys 1024..2047
  const int q0w = qt * 128 + pair * 32;
  const int csb = bh * LL;
  const int kbase = kh2 << 10;          // key offset of this wave's half

  {
    const float* amb = aml2 + b * LL;
    for (int i = tid; i < LL; i += 512) amL[i] = amb[i];
  }

  // Q B-fragments for the two 16-query groups (rotary etc. pre-folded)
  v8h qf0[2], qf1[2];
  v4h bq0, bq1;
  {
    const _Float16* qp = Q + ((size_t)(b * LL + q0w + ql)) * DD + h * 64 + quad * 8;
    qf0[0] = *(const v8h*)qp;
    qf0[1] = *(const v8h*)(qp + 32);
    const v2h c2 = __builtin_bit_cast(v2h, csh2[csb + q0w + ql]);
    v4h t = (v4h){0, 0, 0, 0};
    if (quad == 0) { t[0] = c2[0]; t[1] = c2[1]; }
    bq0 = t;
  }
  {
    const _Float16* qp = Q + ((size_t)(b * LL + q0w + 16 + ql)) * DD + h * 64 + quad * 8;
    qf1[0] = *(const v8h*)qp;
    qf1[1] = *(const v8h*)(qp + 32);
    const v2h c2 = __builtin_bit_cast(v2h, csh2[csb + q0w + 16 + ql]);
    v4h t = (v4h){0, 0, 0, 0};
    if (quad == 0) { t[0] = c2[0]; t[1] = c2[1]; }
    bq1 = t;
  }
  const v4h ones = (v4h){(_Float16)1.f, (_Float16)1.f,
                         (_Float16)1.f, (_Float16)1.f};

  v4f o0[4], o1[4];
#pragma unroll
  for (int nt = 0; nt < 4; ++nt) {
    o0[nt] = (v4f){0.f, 0.f, 0.f, 0.f};
    o1[nt] = (v4f){0.f, 0.f, 0.f, 0.f};
  }
  v4f lacc0 = (v4f){0.f, 0.f, 0.f, 0.f};
  v4f lacc1 = (v4f){0.f, 0.f, 0.f, 0.f};

  const _Float16* Kb   = K + (size_t)(b * LL) * DD + h * 64;     // row stride 1024
  const _Float16* VTb2 = VT2 + (size_t)bh * 131072;              // 32 tiles x 4096
  const unsigned* csk = csh2 + csb;

  // staging: 512 threads move one full 8KB tile per GLD source line
  const int srow = tid >> 3;                // 0..63 K staging row
  const int kch  = (tid & 7) ^ (srow & 7);  // swizzled source 16B chunk (K only)
  const size_t kgb = (size_t)srow * 1024 + kch * 8;

  // prologue: both halves' first tiles (t=0 and t=16) -> buf 0
  {
    GLD(Kb + kgb,                          &Kt[0][0][tid * 8]);
    GLD(Kb + kgb + (size_t)1024 * 1024,    &Kt[1][0][tid * 8]);
    GLD(VTb2 + tid * 8,                    &Vt[0][0][tid * 8]);
    GLD(VTb2 + 65536 + tid * 8,            &Vt[1][0][tid * 8]);
  }
  unsigned cs_cur[4], cs_nxt[4];
#pragma unroll
  for (int c = 0; c < 4; ++c) cs_cur[c] = csk[kbase + c * 16 + ql];
  __syncthreads();

  for (int tt = 0; tt < 8; ++tt) {
#pragma unroll
    for (int u = 0; u < 2; ++u) {          // u == compile-time buffer index
      const int s = tt * 2 + u;            // step 0..15 within each half
      const int k0 = kbase + s * 64;       // absolute key base for this wave
      if (s < 15) {
        const int t1 = s + 1;
        const size_t kg0 = kgb + (size_t)(t1 * 64) * 1024;
        GLD(Kb + kg0,                        &Kt[0][u ^ 1][tid * 8]);
        GLD(Kb + kg0 + (size_t)1024 * 1024,  &Kt[1][u ^ 1][tid * 8]);
        const _Float16* vsrc = VTb2 + (size_t)t1 * 4096;
        GLD(vsrc + tid * 8,          &Vt[0][u ^ 1][tid * 8]);
        GLD(vsrc + 65536 + tid * 8,  &Vt[1][u ^ 1][tid * 8]);
#pragma unroll
        for (int c = 0; c < 4; ++c)
          cs_nxt[c] = csk[kbase + t1 * 64 + c * 16 + ql];
      }
      const _Float16* KtB = Kt[kh2][u];
      const _Float16* VtB = Vt[kh2][u];

      // --- S^T (log2 domain) + mask-dot MFMA, q-groups sharing K frags ---
      v4f st0[4], st1[4], dd0[4], dd1[4];
#pragma unroll
      for (int c = 0; c < 4; ++c) {
        const int row = c * 16 + ql;
        const int sw = row & 7;
        v8h a0 = *(const v8h*)&KtB[row * 64 + ((quad ^ sw) << 3)];
        v8h a1 = *(const v8h*)&KtB[row * 64 + (((quad + 4) ^ sw) << 3)];
        v4f z0 = (v4f){0.f, 0.f, 0.f, 0.f};
        z0 = __builtin_amdgcn_mfma_f32_16x16x32_f16(a0, qf0[0], z0, 0, 0, 0);
        z0 = __builtin_amdgcn_mfma_f32_16x16x32_f16(a1, qf0[1], z0, 0, 0, 0);
        st0[c] = z0;
        v4f z1 = (v4f){0.f, 0.f, 0.f, 0.f};
        z1 = __builtin_amdgcn_mfma_f32_16x16x32_f16(a0, qf1[0], z1, 0, 0, 0);
        z1 = __builtin_amdgcn_mfma_f32_16x16x32_f16(a1, qf1[1], z1, 0, 0, 0);
        st1[c] = z1;
        const v2h c2 = __builtin_bit_cast(v2h, cs_cur[c]);
        v4h a = (v4h){0, 0, 0, 0};
        if (quad == 0) { a[0] = c2[0]; a[1] = c2[1]; }
        dd0[c] = __builtin_amdgcn_mfma_f32_16x16x16f16(
            a, bq0, (v4f){0.f, 0.f, 0.f, 0.f}, 0, 0, 0);
        dd1[c] = __builtin_amdgcn_mfma_f32_16x16x16f16(
            a, bq1, (v4f){0.f, 0.f, 0.f, 0.f}, 0, 0, 0);
      }

      // --- mask + P = exp2(score + am): cmp + cndmask + add + exp2 ---
      v4h pf0[4], pf1[4];
#pragma unroll
      for (int c = 0; c < 4; ++c) {
        const v4f am4 = *(const v4f*)&amL[k0 + c * 16 + quad * 4];
        float p0[4], p1[4];
#pragma unroll
        for (int r = 0; r < 4; ++r) {
          p0[r] = __builtin_amdgcn_exp2f(
              ((dd0[c][r] < -0.7f) ? NEGB : st0[c][r]) + am4[r]);
          p1[r] = __builtin_amdgcn_exp2f(
              ((dd1[c][r] < -0.7f) ? NEGB : st1[c][r]) + am4[r]);
        }
        const unsigned a01 = __builtin_bit_cast(
            unsigned, __builtin_amdgcn_cvt_pkrtz(p0[0], p0[1]));
        const unsigned a23 = __builtin_bit_cast(
            unsigned, __builtin_amdgcn_cvt_pkrtz(p0[2], p0[3]));
        pf0[c] = __builtin_bit_cast(v4h, make_uint2(a01, a23));
        const unsigned b01 = __builtin_bit_cast(
            unsigned, __builtin_amdgcn_cvt_pkrtz(p1[0], p1[1]));
        const unsigned b23 = __builtin_bit_cast(
            unsigned, __builtin_amdgcn_cvt_pkrtz(p1[2], p1[3]));
        pf1[c] = __builtin_bit_cast(v4h, make_uint2(b01, b23));
      }

      // --- PV + row-sum, V frags shared by both q-groups (pure MFMA) ---
      __builtin_amdgcn_s_setprio(1);
#pragma unroll
      for (int c = 0; c < 4; ++c) {
        lacc0 = __builtin_amdgcn_mfma_f32_16x16x16f16(pf0[c], ones, lacc0, 0, 0, 0);
        lacc1 = __builtin_amdgcn_mfma_f32_16x16x16f16(pf1[c], ones, lacc1, 0, 0, 0);
#pragma unroll
        for (int nt = 0; nt < 4; ++nt) {
          const v4h vv = *(const v4h*)&VtB[((c * 4 + quad) * 64 +
                                            nt * 16 + ql) * 4];
          o0[nt] = __builtin_amdgcn_mfma_f32_16x16x16f16(pf0[c], vv, o0[nt], 0, 0, 0);
          o1[nt] = __builtin_amdgcn_mfma_f32_16x16x16f16(pf1[c], vv, o1[nt], 0, 0, 0);
        }
      }
      __builtin_amdgcn_s_setprio(0);
#pragma unroll
      for (int c = 0; c < 4; ++c) cs_cur[c] = cs_nxt[c];
      __syncthreads();
    }
  }

  // --- combine K-halves: odd wave writes partials to LDS, even wave adds ---
  v4f* shO = (v4f*)&Kt[0][0][0];   // 4 pairs x 64 lanes x 8 v4f = 32 KB
  v4f* shL = (v4f*)&Vt[0][0][0];   // 4 pairs x 64 lanes x 2 v4f = 8 KB
  if (kh2 == 1) {
    const int ob = (pair * 64 + lane) * 8;
#pragma unroll
    for (int nt = 0; nt < 4; ++nt) {
      shO[ob + nt]     = o0[nt];
      shO[ob + 4 + nt] = o1[nt];
    }
    shL[(pair * 64 + lane) * 2]     = lacc0;
    shL[(pair * 64 + lane) * 2 + 1] = lacc1;
  }
  __syncthreads();
  if (kh2 == 0) {
    const int ob = (pair * 64 + lane) * 8;
#pragma unroll
    for (int nt = 0; nt < 4; ++nt) {
      o0[nt] += shO[ob + nt];
      o1[nt] += shO[ob + 4 + nt];
    }
    lacc0 += shL[(pair * 64 + lane) * 2];
    lacc1 += shL[(pair * 64 + lane) * 2 + 1];

    // epilogue: lacc is in O's row layout (query = g*16 + quad*4 + r)
#pragma unroll
    for (int g = 0; g < 2; ++g) {
      const v4f* op = g ? o1 : o0;
      const v4f la = g ? lacc1 : lacc0;
#pragma unroll
      for (int r = 0; r < 4; ++r) {
        const int q = q0w + g * 16 + quad * 4 + r;
        const float lr = la[r];
        const size_t ob2 = (size_t)(b * LL + q) * DD + h * 64 + ql;
        if (lr <= 0.f) {  // all-masked fallback (never taken with am=0)
          const _Float16* vsrc = VTb2 + (q >> 6) * 4096 +
                                 ((q >> 2) & 15) * 256 + (q & 3);
#pragma unroll
          for (int nt = 0; nt < 4; ++nt)
            ctx[ob2 + nt * 16] = vsrc[(nt * 16 + ql) * 4];
        } else {
          const float inv = 1.f / lr;
          ctx[ob2 + 0]  = (_Float16)(op[0][r] * inv);
          ctx[ob2 + 16] = (_Float16)(op[1][r] * inv);
          ctx[ob2 + 32] = (_Float16)(op[2][r] * inv);
          ctx[ob2 + 48] = (_Float16)(op[3][r] * inv);
        }
      }
    }
  }
}

// ---------------------------------------------------------------------------
// LayerNorm over D=1024, float4 loads/stores
// ---------------------------------------------------------------------------
__global__ __launch_bounds__(256) void layernorm(
    const float* __restrict__ x, const float* __restrict__ g,
    const float* __restrict__ bta, float* __restrict__ out)
{
  __shared__ float red[8];
  const int row = blockIdx.x;
  const int tid = threadIdx.x;
  const float4 vv = ((const float4*)(x + (size_t)row * DD))[tid];
  float lsum = vv.x + vv.y + vv.z + vv.w;
  float lsq  = vv.x * vv.x + vv.y * vv.y + vv.z * vv.z + vv.w * vv.w;
#pragma unroll
  for (int off = 32; off > 0; off >>= 1) {
    lsum += __shfl_down(lsum, off, 64);
    lsq  += __shfl_down(lsq,  off, 64);
  }
  const int wid = tid >> 6;
  if ((tid & 63) == 0) { red[wid] = lsum; red[wid + 4] = lsq; }
  __syncthreads();
  const float tsum = red[0] + red[1] + red[2] + red[3];
  const float tsq  = red[4] + red[5] + red[6] + red[7];
  const float mean = tsum * (1.f / DD);
  const float var  = tsq * (1.f / DD) - mean * mean;
  const float inv  = rsqrtf(var + 1e-12f);
  const float4 gg = ((const float4*)g)[tid];
  const float4 bb = ((const float4*)bta)[tid];
  float4 oo;
  oo.x = (vv.x - mean) * inv * gg.x + bb.x;
  oo.y = (vv.y - mean) * inv * gg.y + bb.y;
  oo.z = (vv.z - mean) * inv * gg.z + bb.z;
  oo.w = (vv.w - mean) * inv * gg.w + bb.w;
  ((float4*)(out + (size_t)row * DD))[tid] = oo;
}

// ---------------------------------------------------------------------------
extern "C" void kernel_launch(void* const* d_in, const int* in_sizes, int n_in,
                              void* d_out, int out_size, void* d_ws, size_t ws_size,
                              hipStream_t stream)
{
  const float* hs  = (const float*)d_in[0];
  const float* amk = (const float*)d_in[1];
  const float* phi = (const float*)d_in[2];
  const float* Wq  = (const float*)d_in[3];
  const float* bq  = (const float*)d_in[4];
  const float* Wk  = (const float*)d_in[5];
  const float* bk  = (const float*)d_in[6];
  const float* Wv  = (const float*)d_in[7];
  const float* bv  = (const float*)d_in[8];
  const float* Wo  = (const float*)d_in[9];
  const float* bo  = (const float*)d_in[10];
  const float* lng = (const float*)d_in[11];
  const float* lnb = (const float*)d_in[12];
  float* out = (float*)d_out;

  const size_t SZ = (size_t)BB * LL * DD;   // 4 M elements
  _Float16* hsh   = (_Float16*)d_ws;
  _Float16* qh    = hsh + SZ;
  _Float16* kh    = qh + SZ;
  _Float16* vt2   = kh + SZ;                // 4 M (V pre-tiled VT2)
  _Float16* ctxh  = vt2 + SZ;
  _Float16* wqkvh = ctxh + SZ;              // 3 M
  _Float16* woh   = wqkvh + 3 * (size_t)DD * DD;  // 1 M
  float* xb    = (float*)(woh + (size_t)DD * DD);
  unsigned* csh2 = (unsigned*)(xb + SZ);    // B*H*L packed {cos,sin} f16
  float* aml2 = (float*)(csh2 + (size_t)BB * HH * LL);  // B*L am*log2e

  prep<<<8448, 256, 0, stream>>>(hs, Wq, Wk, Wv, Wo, phi, amk,
                                 hsh, wqkvh, woh, csh2, aml2);
  gemm_qkv<<<dim3(24, 32), 256, 0, stream>>>(hsh, wqkvh, bq, bk, bv, csh2,
                                             qh, kh, vt2);
  attn_db<<<512, 512, 0, stream>>>(qh, kh, vt2, csh2, aml2, ctxh);
  gemm_o<<<dim3(16, 32), 256, 0, stream>>>(ctxh, woh, bo, hs, xb);
  layernorm<<<BB * LL, 256, 0, stream>>>(xb, lng, lnb, out);
}

// Round 11
// 246.821 us; speedup vs baseline: 1.4117x; 1.2110x over previous
//
#include <hip/hip_runtime.h>
#include <cmath>

#define BB 2
#define LL 2048
#define DD 1024
#define HH 16
#define HDD 64

typedef _Float16 v8h __attribute__((ext_vector_type(8)));
typedef _Float16 v4h __attribute__((ext_vector_type(4)));
typedef _Float16 v2h __attribute__((ext_vector_type(2)));
typedef float v4f __attribute__((ext_vector_type(4)));

#define LOG2E 1.44269504089f
#define NEGB  (-1.442695e9f)      /* -1e9 * log2e */

// async global->LDS, 16B per lane.
#define GLD(gp, lp)                                                        \
  __builtin_amdgcn_global_load_lds(                                        \
      (const __attribute__((address_space(1))) void*)(gp),                 \
      (__attribute__((address_space(3))) void*)(lp), 16, 0, 0)

// ---------------------------------------------------------------------------
// Fused prep: fp32->f16 cvt (hs, Wq/Wk/Wv, Wo) + cos/sin table + am*log2e.
// ---------------------------------------------------------------------------
__global__ __launch_bounds__(256) void prep(
    const float* __restrict__ hs, const float* __restrict__ wq,
    const float* __restrict__ wk, const float* __restrict__ wv,
    const float* __restrict__ wo, const float* __restrict__ phi,
    const float* __restrict__ amk, _Float16* __restrict__ hsh,
    _Float16* __restrict__ wqkvh, _Float16* __restrict__ woh,
    unsigned* __restrict__ csh2, float* __restrict__ aml2)
{
  const int i = blockIdx.x * 256 + threadIdx.x;
  if (i < 2097152) {
    const float* s;
    _Float16* d;
    if (i < 1048576)      { s = hs + (size_t)i * 4;            d = hsh + (size_t)i * 4; }
    else if (i < 1310720) { int j = i - 1048576; s = wq + (size_t)j * 4; d = wqkvh + (size_t)j * 4; }
    else if (i < 1572864) { int j = i - 1310720; s = wk + (size_t)j * 4; d = wqkvh + 1048576 + (size_t)j * 4; }
    else if (i < 1835008) { int j = i - 1572864; s = wv + (size_t)j * 4; d = wqkvh + 2097152 + (size_t)j * 4; }
    else                  { int j = i - 1835008; s = wo + (size_t)j * 4; d = woh + (size_t)j * 4; }
    float4 v = *(const float4*)s;
    v4h o;
    o[0] = (_Float16)v.x; o[1] = (_Float16)v.y;
    o[2] = (_Float16)v.z; o[3] = (_Float16)v.w;
    *(v4h*)d = o;
  } else {
    const int o = i - 2097152;                   // 0..65535 = B*H*L
    if (o < BB * LL) aml2[o] = amk[o] * LOG2E;
    const int l = o & 2047;
    const int h = (o >> 11) & 15;
    const int b = o >> 15;
    const float ph = phi[(b * 2048 + l) * 16 + h];
    v2h cs;
    cs[0] = (_Float16)cosf(ph);
    cs[1] = (_Float16)sinf(ph);
    csh2[o] = __builtin_bit_cast(unsigned, cs);
  }
}

// ---------------------------------------------------------------------------
// m97-style MFMA GEMM core: 128x128 tile, BK=32, 256 thr.
// ---------------------------------------------------------------------------
__device__ __forceinline__ void gemm_loop(
    const _Float16* __restrict__ A, const _Float16* __restrict__ W, const int K,
    const int m0, const int n0, const int tid, const int wave, const int lane,
    _Float16* As, _Float16* Bs, v4f acc[4][4])
{
  const int quad = lane >> 4;
  const int ql = lane & 15;
  const int wm = (wave >> 1) * 64;
  const int wn = (wave & 1) * 64;
  const int srow = tid >> 2;
  const int skof = (tid & 3) * 8;
  const _Float16* Ap = A + (size_t)(m0 + srow) * K + skof;
  const _Float16* Wp = W + (size_t)(n0 + srow) * K + skof;
  const size_t rstep = (size_t)64 * K;
  for (int k0 = 0; k0 < K; k0 += 32) {
    __syncthreads();
    GLD(Ap + k0,         As + tid * 8);
    GLD(Ap + rstep + k0, As + 2048 + tid * 8);
    GLD(Wp + k0,         Bs + tid * 8);
    GLD(Wp + rstep + k0, Bs + 2048 + tid * 8);
    __syncthreads();
    v8h af[4], bf[4];
#pragma unroll
    for (int mt = 0; mt < 4; ++mt)
      af[mt] = *(const v8h*)&As[(wm + mt * 16 + ql) * 32 + quad * 8];
#pragma unroll
    for (int nt = 0; nt < 4; ++nt)
      bf[nt] = *(const v8h*)&Bs[(wn + nt * 16 + ql) * 32 + quad * 8];
#pragma unroll
    for (int mt = 0; mt < 4; ++mt)
#pragma unroll
      for (int nt = 0; nt < 4; ++nt)
        acc[mt][nt] = __builtin_amdgcn_mfma_f32_16x16x32_f16(
            af[mt], bf[nt], acc[mt][nt], 0, 0, 0);
  }
}

// ---------------------------------------------------------------------------
// Fused QKV GEMM (XCD-swizzled). Epilogue:
//   q-band: +bias, rotary (fp32), scale by (1/8)*log2e, single f16 rounding
//   k-band: +bias, rotary (fp32), f16
//   v-band: +bias, written directly in VT2 layout (8B unit [j=key>>2][d])
// ---------------------------------------------------------------------------
__global__ __launch_bounds__(256) void gemm_qkv(
    const _Float16* __restrict__ A, const _Float16* __restrict__ W,
    const float* __restrict__ bqp, const float* __restrict__ bkp,
    const float* __restrict__ bvp, const unsigned* __restrict__ csh2,
    _Float16* __restrict__ qh, _Float16* __restrict__ kh,
    _Float16* __restrict__ vt2)
{
  __shared__ _Float16 As[128 * 32];
  __shared__ _Float16 Bs[128 * 32];
  const int tid = threadIdx.x, lane = tid & 63, wave = tid >> 6;
  const int quad = lane >> 4, ql = lane & 15;
  const int bid0 = blockIdx.y * 24 + blockIdx.x;
  const int bid  = (bid0 & 7) * 96 + (bid0 >> 3);
  const int m0 = (bid / 24) * 128, n0 = (bid % 24) * 128;
  v4f acc[4][4];
#pragma unroll
  for (int mt = 0; mt < 4; ++mt)
#pragma unroll
    for (int nt = 0; nt < 4; ++nt) acc[mt][nt] = (v4f){0.f, 0.f, 0.f, 0.f};
  gemm_loop(A, W, DD, m0, n0, tid, wave, lane, As, Bs, acc);

  const int buf = n0 >> 10;                       // 0=q 1=k 2=v
  const int col0 = (n0 & 1023) + (wave & 1) * 64; // 64-col band == one head
  const int hh = col0 >> 6;
  const int mr0 = m0 + (wave >> 1) * 64;

  if (buf == 2) {
    float bb4[4];
#pragma unroll
    for (int nt = 0; nt < 4; ++nt) bb4[nt] = bvp[col0 + nt * 16 + ql];
#pragma unroll
    for (int mt = 0; mt < 4; ++mt) {
      const int row = mr0 + mt * 16 + quad * 4;   // keys row..row+3
      const int b_ = row >> 11;
      const int l = row & 2047;
      _Float16* dst = vt2 + ((size_t)(b_ * 16 + hh) * 32 + (l >> 6)) * 4096 +
                      ((l >> 2) & 15) * 256;
#pragma unroll
      for (int nt = 0; nt < 4; ++nt) {
        const int d = nt * 16 + ql;
        v4h o4;
#pragma unroll
        for (int r = 0; r < 4; ++r) o4[r] = (_Float16)(acc[mt][nt][r] + bb4[nt]);
        *(v4h*)&dst[d * 4] = o4;
      }
    }
  } else {
    const float scl = (buf == 0) ? 0.125f * LOG2E : 1.0f;
    _Float16* outp = (buf == 0) ? qh : kh;
    const float* bias = (buf == 0) ? bqp : bkp;
    float bb4[4];
#pragma unroll
    for (int nt = 0; nt < 4; ++nt) bb4[nt] = bias[col0 + nt * 16 + ql];
#pragma unroll
    for (int mt = 0; mt < 4; ++mt)
#pragma unroll
      for (int r = 0; r < 4; ++r) {
        const int row = mr0 + mt * 16 + quad * 4 + r;
        const int b_ = row >> 11;
        const int l = row & 2047;
        const v2h c2 = __builtin_bit_cast(
            v2h, csh2[(b_ * 16 + hh) * 2048 + l]);
        const float c = (float)c2[0], s = (float)c2[1];
        _Float16* orow = outp + (size_t)row * DD + col0 + ql;
#pragma unroll
        for (int pp = 0; pp < 2; ++pp) {
          const float a0 = acc[mt][pp][r] + bb4[pp];
          const float a1 = acc[mt][pp + 2][r] + bb4[pp + 2];
          orow[pp * 16]        = (_Float16)((a0 * c - a1 * s) * scl);
          orow[(pp + 2) * 16]  = (_Float16)((a1 * c + a0 * s) * scl);
        }
      }
  }
}

// ---------------------------------------------------------------------------
// O-proj GEMM, 128(M)x64(N) tiles: 512 blocks (2/CU), XCD-swizzled.
// ---------------------------------------------------------------------------
__global__ __launch_bounds__(256) void gemm_o(
    const _Float16* __restrict__ A, const _Float16* __restrict__ W,
    const float* __restrict__ bo, const float* __restrict__ res,
    float* __restrict__ out)
{
  __shared__ _Float16 As[128 * 32];
  __shared__ _Float16 Bs[64 * 32];
  const int tid = threadIdx.x, lane = tid & 63, wave = tid >> 6;
  const int quad = lane >> 4, ql = lane & 15;
  const int bid0 = blockIdx.y * 16 + blockIdx.x;
  const int bid  = (bid0 & 7) * 64 + (bid0 >> 3);
  const int m0 = (bid / 16) * 128, n0 = (bid % 16) * 64;
  v4f acc[4][2];
#pragma unroll
  for (int mt = 0; mt < 4; ++mt)
#pragma unroll
    for (int nt = 0; nt < 2; ++nt) acc[mt][nt] = (v4f){0.f, 0.f, 0.f, 0.f};
  const int wm = (wave >> 1) * 64;
  const int wn = (wave & 1) * 32;
  const int srow = tid >> 2;
  const int skof = (tid & 3) * 8;
  const _Float16* Ap = A + (size_t)(m0 + srow) * DD + skof;
  const _Float16* Wp = W + (size_t)(n0 + srow) * DD + skof;
  const size_t rstep = (size_t)64 * DD;
  for (int k0 = 0; k0 < DD; k0 += 32) {
    __syncthreads();
    GLD(Ap + k0,         As + tid * 8);
    GLD(Ap + rstep + k0, As + 2048 + tid * 8);
    GLD(Wp + k0,         Bs + tid * 8);
    __syncthreads();
    v8h af[4], bf[2];
#pragma unroll
    for (int mt = 0; mt < 4; ++mt)
      af[mt] = *(const v8h*)&As[(wm + mt * 16 + ql) * 32 + quad * 8];
#pragma unroll
    for (int nt = 0; nt < 2; ++nt)
      bf[nt] = *(const v8h*)&Bs[(wn + nt * 16 + ql) * 32 + quad * 8];
#pragma unroll
    for (int mt = 0; mt < 4; ++mt)
#pragma unroll
      for (int nt = 0; nt < 2; ++nt)
        acc[mt][nt] = __builtin_amdgcn_mfma_f32_16x16x32_f16(
            af[mt], bf[nt], acc[mt][nt], 0, 0, 0);
  }
#pragma unroll
  for (int nt = 0; nt < 2; ++nt) {
    const int col = n0 + wn + nt * 16 + ql;
    const float bb = bo[col];
#pragma unroll
    for (int mt = 0; mt < 4; ++mt)
#pragma unroll
      for (int r = 0; r < 4; ++r) {
        const int row = m0 + wm + mt * 16 + quad * 4 + r;
        const size_t ix = (size_t)row * DD + col;
        out[ix] = acc[mt][nt][r] + bb + res[ix];
      }
  }
}

// ---------------------------------------------------------------------------
// K-SPLIT flash attention, spill-fixed (resubmission of R9-fix: R10's bench
// was an infrastructure failure, not a kernel verdict; source re-audited for
// barrier uniformity, bounds, and resource limits).
// R9's structure was right (occupancy 41%) but __launch_bounds__(512,4) was
// interpreted as 4 BLOCKS/CU -> 64-VGPR cap -> ~470MB scratch spill traffic.
// Fix 1: __launch_bounds__(512, 2) -> cap >=128 VGPR, no spill; occupancy
//   stays 2 blocks/CU (LDS-limited at 72KB) = 16 waves/CU = 4/SIMD.
// Fix 2: combine epilogue uses nt-major LDS layout (16B lane stride,
//   conflict-free) -- R9's pair-major had 128B lane stride = 32-way conflict.
// Wave pairs (even=keys 0..1023, odd=1024..2047) cover the SAME 32 queries;
// partial o/l sums combine EXACTLY (pure-sum softmax, no online max) via one
// LDS exchange. 16 steps/wave. setprio kept around PV.
// ---------------------------------------------------------------------------
__global__ __launch_bounds__(512, 2) void attn_db(
    const _Float16* __restrict__ Q, const _Float16* __restrict__ K,
    const _Float16* __restrict__ VT2, const unsigned* __restrict__ csh2,
    const float* __restrict__ aml2, _Float16* __restrict__ ctx)
{
  __shared__ _Float16 Kt[2][2][4096];   // [khalf][buf] 64 rows x 64 dims
  __shared__ _Float16 Vt[2][2][4096];   // [khalf][buf] VT2 tile image
  __shared__ float amL[LL];             // am * log2e: 8 KB

  const int tid  = threadIdx.x;         // 0..511
  const int lane = tid & 63;
  const int wave = tid >> 6;            // 0..7
  const int quad = lane >> 4;
  const int ql   = lane & 15;
  const int bid  = blockIdx.x;          // 512 = 16 qt * 32 bh
  const int bh = bid & 31;              // XCD swizzle: same (b,h) -> same XCD
  const int qt = bid >> 5;
  const int h  = bh & 15;
  const int b  = bh >> 4;
  const int pair = wave >> 1;           // 0..3: which 32-query slice
  const int kh2  = wave & 1;            // 0: keys 0..1023, 1: keys 1024..2047
  const int q0w = qt * 128 + pair * 32;
  const int csb = bh * LL;
  const int kbase = kh2 << 10;          // key offset of this wave's half

  {
    const float* amb = aml2 + b * LL;
    for (int i = tid; i < LL; i += 512) amL[i] = amb[i];
  }

  // Q B-fragments for the two 16-query groups (rotary etc. pre-folded)
  v8h qf0[2], qf1[2];
  v4h bq0, bq1;
  {
    const _Float16* qp = Q + ((size_t)(b * LL + q0w + ql)) * DD + h * 64 + quad * 8;
    qf0[0] = *(const v8h*)qp;
    qf0[1] = *(const v8h*)(qp + 32);
    const v2h c2 = __builtin_bit_cast(v2h, csh2[csb + q0w + ql]);
    v4h t = (v4h){0, 0, 0, 0};
    if (quad == 0) { t[0] = c2[0]; t[1] = c2[1]; }
    bq0 = t;
  }
  {
    const _Float16* qp = Q + ((size_t)(b * LL + q0w + 16 + ql)) * DD + h * 64 + quad * 8;
    qf1[0] = *(const v8h*)qp;
    qf1[1] = *(const v8h*)(qp + 32);
    const v2h c2 = __builtin_bit_cast(v2h, csh2[csb + q0w + 16 + ql]);
    v4h t = (v4h){0, 0, 0, 0};
    if (quad == 0) { t[0] = c2[0]; t[1] = c2[1]; }
    bq1 = t;
  }
  const v4h ones = (v4h){(_Float16)1.f, (_Float16)1.f,
                         (_Float16)1.f, (_Float16)1.f};

  v4f o0[4], o1[4];
#pragma unroll
  for (int nt = 0; nt < 4; ++nt) {
    o0[nt] = (v4f){0.f, 0.f, 0.f, 0.f};
    o1[nt] = (v4f){0.f, 0.f, 0.f, 0.f};
  }
  v4f lacc0 = (v4f){0.f, 0.f, 0.f, 0.f};
  v4f lacc1 = (v4f){0.f, 0.f, 0.f, 0.f};

  const _Float16* Kb   = K + (size_t)(b * LL) * DD + h * 64;     // row stride 1024
  const _Float16* VTb2 = VT2 + (size_t)bh * 131072;              // 32 tiles x 4096
  const unsigned* csk = csh2 + csb;

  // staging: 512 threads move one full 8KB tile per GLD source line
  const int srow = tid >> 3;                // 0..63 K staging row
  const int kch  = (tid & 7) ^ (srow & 7);  // swizzled source 16B chunk (K only)
  const size_t kgb = (size_t)srow * 1024 + kch * 8;

  // prologue: both halves' first tiles (t=0 and t=16) -> buf 0
  {
    GLD(Kb + kgb,                          &Kt[0][0][tid * 8]);
    GLD(Kb + kgb + (size_t)1024 * 1024,    &Kt[1][0][tid * 8]);
    GLD(VTb2 + tid * 8,                    &Vt[0][0][tid * 8]);
    GLD(VTb2 + 65536 + tid * 8,            &Vt[1][0][tid * 8]);
  }
  unsigned cs_cur[4], cs_nxt[4];
#pragma unroll
  for (int c = 0; c < 4; ++c) cs_cur[c] = csk[kbase + c * 16 + ql];
  __syncthreads();

  for (int tt = 0; tt < 8; ++tt) {
#pragma unroll
    for (int u = 0; u < 2; ++u) {          // u == compile-time buffer index
      const int s = tt * 2 + u;            // step 0..15 within each half
      const int k0 = kbase + s * 64;       // absolute key base for this wave
      if (s < 15) {
        const int t1 = s + 1;
        const size_t kg0 = kgb + (size_t)(t1 * 64) * 1024;
        GLD(Kb + kg0,                        &Kt[0][u ^ 1][tid * 8]);
        GLD(Kb + kg0 + (size_t)1024 * 1024,  &Kt[1][u ^ 1][tid * 8]);
        const _Float16* vsrc = VTb2 + (size_t)t1 * 4096;
        GLD(vsrc + tid * 8,          &Vt[0][u ^ 1][tid * 8]);
        GLD(vsrc + 65536 + tid * 8,  &Vt[1][u ^ 1][tid * 8]);
#pragma unroll
        for (int c = 0; c < 4; ++c)
          cs_nxt[c] = csk[kbase + t1 * 64 + c * 16 + ql];
      }
      const _Float16* KtB = Kt[kh2][u];
      const _Float16* VtB = Vt[kh2][u];

      // --- S^T (log2 domain) + mask-dot MFMA, q-groups sharing K frags ---
      v4f st0[4], st1[4], dd0[4], dd1[4];
#pragma unroll
      for (int c = 0; c < 4; ++c) {
        const int row = c * 16 + ql;
        const int sw = row & 7;
        v8h a0 = *(const v8h*)&KtB[row * 64 + ((quad ^ sw) << 3)];
        v8h a1 = *(const v8h*)&KtB[row * 64 + (((quad + 4) ^ sw) << 3)];
        v4f z0 = (v4f){0.f, 0.f, 0.f, 0.f};
        z0 = __builtin_amdgcn_mfma_f32_16x16x32_f16(a0, qf0[0], z0, 0, 0, 0);
        z0 = __builtin_amdgcn_mfma_f32_16x16x32_f16(a1, qf0[1], z0, 0, 0, 0);
        st0[c] = z0;
        v4f z1 = (v4f){0.f, 0.f, 0.f, 0.f};
        z1 = __builtin_amdgcn_mfma_f32_16x16x32_f16(a0, qf1[0], z1, 0, 0, 0);
        z1 = __builtin_amdgcn_mfma_f32_16x16x32_f16(a1, qf1[1], z1, 0, 0, 0);
        st1[c] = z1;
        const v2h c2 = __builtin_bit_cast(v2h, cs_cur[c]);
        v4h a = (v4h){0, 0, 0, 0};
        if (quad == 0) { a[0] = c2[0]; a[1] = c2[1]; }
        dd0[c] = __builtin_amdgcn_mfma_f32_16x16x16f16(
            a, bq0, (v4f){0.f, 0.f, 0.f, 0.f}, 0, 0, 0);
        dd1[c] = __builtin_amdgcn_mfma_f32_16x16x16f16(
            a, bq1, (v4f){0.f, 0.f, 0.f, 0.f}, 0, 0, 0);
      }

      // --- mask + P = exp2(score + am): cmp + cndmask + add + exp2 ---
      v4h pf0[4], pf1[4];
#pragma unroll
      for (int c = 0; c < 4; ++c) {
        const v4f am4 = *(const v4f*)&amL[k0 + c * 16 + quad * 4];
        float p0[4], p1[4];
#pragma unroll
        for (int r = 0; r < 4; ++r) {
          p0[r] = __builtin_amdgcn_exp2f(
              ((dd0[c][r] < -0.7f) ? NEGB : st0[c][r]) + am4[r]);
          p1[r] = __builtin_amdgcn_exp2f(
              ((dd1[c][r] < -0.7f) ? NEGB : st1[c][r]) + am4[r]);
        }
        const unsigned a01 = __builtin_bit_cast(
            unsigned, __builtin_amdgcn_cvt_pkrtz(p0[0], p0[1]));
        const unsigned a23 = __builtin_bit_cast(
            unsigned, __builtin_amdgcn_cvt_pkrtz(p0[2], p0[3]));
        pf0[c] = __builtin_bit_cast(v4h, make_uint2(a01, a23));
        const unsigned b01 = __builtin_bit_cast(
            unsigned, __builtin_amdgcn_cvt_pkrtz(p1[0], p1[1]));
        const unsigned b23 = __builtin_bit_cast(
            unsigned, __builtin_amdgcn_cvt_pkrtz(p1[2], p1[3]));
        pf1[c] = __builtin_bit_cast(v4h, make_uint2(b01, b23));
      }

      // --- PV + row-sum, V frags shared by both q-groups (pure MFMA) ---
      __builtin_amdgcn_s_setprio(1);
#pragma unroll
      for (int c = 0; c < 4; ++c) {
        lacc0 = __builtin_amdgcn_mfma_f32_16x16x16f16(pf0[c], ones, lacc0, 0, 0, 0);
        lacc1 = __builtin_amdgcn_mfma_f32_16x16x16f16(pf1[c], ones, lacc1, 0, 0, 0);
#pragma unroll
        for (int nt = 0; nt < 4; ++nt) {
          const v4h vv = *(const v4h*)&VtB[((c * 4 + quad) * 64 +
                                            nt * 16 + ql) * 4];
          o0[nt] = __builtin_amdgcn_mfma_f32_16x16x16f16(pf0[c], vv, o0[nt], 0, 0, 0);
          o1[nt] = __builtin_amdgcn_mfma_f32_16x16x16f16(pf1[c], vv, o1[nt], 0, 0, 0);
        }
      }
      __builtin_amdgcn_s_setprio(0);
#pragma unroll
      for (int c = 0; c < 4; ++c) cs_cur[c] = cs_nxt[c];
      __syncthreads();
    }
  }

  // --- combine K-halves (nt-major layout: 16B lane stride, conflict-free) ---
  v4f* shO = (v4f*)&Kt[0][0][0];   // 8 x 256 v4f = 32 KB
  v4f* shL = (v4f*)&Vt[0][0][0];   // 2 x 256 v4f = 8 KB
  const int sl = pair * 64 + lane;
  if (kh2 == 1) {
#pragma unroll
    for (int nt = 0; nt < 4; ++nt) {
      shO[nt * 256 + sl]       = o0[nt];
      shO[(4 + nt) * 256 + sl] = o1[nt];
    }
    shL[sl]       = lacc0;
    shL[256 + sl] = lacc1;
  }
  __syncthreads();
  if (kh2 == 0) {
#pragma unroll
    for (int nt = 0; nt < 4; ++nt) {
      o0[nt] += shO[nt * 256 + sl];
      o1[nt] += shO[(4 + nt) * 256 + sl];
    }
    lacc0 += shL[sl];
    lacc1 += shL[256 + sl];

    // epilogue: lacc is in O's row layout (query = g*16 + quad*4 + r)
#pragma unroll
    for (int g = 0; g < 2; ++g) {
      const v4f* op = g ? o1 : o0;
      const v4f la = g ? lacc1 : lacc0;
#pragma unroll
      for (int r = 0; r < 4; ++r) {
        const int q = q0w + g * 16 + quad * 4 + r;
        const float lr = la[r];
        const size_t ob2 = (size_t)(b * LL + q) * DD + h * 64 + ql;
        if (lr <= 0.f) {  // all-masked fallback (never taken with am=0)
          const _Float16* vsrc = VTb2 + (q >> 6) * 4096 +
                                 ((q >> 2) & 15) * 256 + (q & 3);
#pragma unroll
          for (int nt = 0; nt < 4; ++nt)
            ctx[ob2 + nt * 16] = vsrc[(nt * 16 + ql) * 4];
        } else {
          const float inv = 1.f / lr;
          ctx[ob2 + 0]  = (_Float16)(op[0][r] * inv);
          ctx[ob2 + 16] = (_Float16)(op[1][r] * inv);
          ctx[ob2 + 32] = (_Float16)(op[2][r] * inv);
          ctx[ob2 + 48] = (_Float16)(op[3][r] * inv);
        }
      }
    }
  }
}

// ---------------------------------------------------------------------------
// LayerNorm over D=1024, float4 loads/stores
// ---------------------------------------------------------------------------
__global__ __launch_bounds__(256) void layernorm(
    const float* __restrict__ x, const float* __restrict__ g,
    const float* __restrict__ bta, float* __restrict__ out)
{
  __shared__ float red[8];
  const int row = blockIdx.x;
  const int tid = threadIdx.x;
  const float4 vv = ((const float4*)(x + (size_t)row * DD))[tid];
  float lsum = vv.x + vv.y + vv.z + vv.w;
  float lsq  = vv.x * vv.x + vv.y * vv.y + vv.z * vv.z + vv.w * vv.w;
#pragma unroll
  for (int off = 32; off > 0; off >>= 1) {
    lsum += __shfl_down(lsum, off, 64);
    lsq  += __shfl_down(lsq,  off, 64);
  }
  const int wid = tid >> 6;
  if ((tid & 63) == 0) { red[wid] = lsum; red[wid + 4] = lsq; }
  __syncthreads();
  const float tsum = red[0] + red[1] + red[2] + red[3];
  const float tsq  = red[4] + red[5] + red[6] + red[7];
  const float mean = tsum * (1.f / DD);
  const float var  = tsq * (1.f / DD) - mean * mean;
  const float inv  = rsqrtf(var + 1e-12f);
  const float4 gg = ((const float4*)g)[tid];
  const float4 bb = ((const float4*)bta)[tid];
  float4 oo;
  oo.x = (vv.x - mean) * inv * gg.x + bb.x;
  oo.y = (vv.y - mean) * inv * gg.y + bb.y;
  oo.z = (vv.z - mean) * inv * gg.z + bb.z;
  oo.w = (vv.w - mean) * inv * gg.w + bb.w;
  ((float4*)(out + (size_t)row * DD))[tid] = oo;
}

// ---------------------------------------------------------------------------
extern "C" void kernel_launch(void* const* d_in, const int* in_sizes, int n_in,
                              void* d_out, int out_size, void* d_ws, size_t ws_size,
                              hipStream_t stream)
{
  const float* hs  = (const float*)d_in[0];
  const float* amk = (const float*)d_in[1];
  const float* phi = (const float*)d_in[2];
  const float* Wq  = (const float*)d_in[3];
  const float* bq  = (const float*)d_in[4];
  const float* Wk  = (const float*)d_in[5];
  const float* bk  = (const float*)d_in[6];
  const float* Wv  = (const float*)d_in[7];
  const float* bv  = (const float*)d_in[8];
  const float* Wo  = (const float*)d_in[9];
  const float* bo  = (const float*)d_in[10];
  const float* lng = (const float*)d_in[11];
  const float* lnb = (const float*)d_in[12];
  float* out = (float*)d_out;

  const size_t SZ = (size_t)BB * LL * DD;   // 4 M elements
  _Float16* hsh   = (_Float16*)d_ws;
  _Float16* qh    = hsh + SZ;
  _Float16* kh    = qh + SZ;
  _Float16* vt2   = kh + SZ;                // 4 M (V pre-tiled VT2)
  _Float16* ctxh  = vt2 + SZ;
  _Float16* wqkvh = ctxh + SZ;              // 3 M
  _Float16* woh   = wqkvh + 3 * (size_t)DD * DD;  // 1 M
  float* xb    = (float*)(woh + (size_t)DD * DD);
  unsigned* csh2 = (unsigned*)(xb + SZ);    // B*H*L packed {cos,sin} f16
  float* aml2 = (float*)(csh2 + (size_t)BB * HH * LL);  // B*L am*log2e

  prep<<<8448, 256, 0, stream>>>(hs, Wq, Wk, Wv, Wo, phi, amk,
                                 hsh, wqkvh, woh, csh2, aml2);
  gemm_qkv<<<dim3(24, 32), 256, 0, stream>>>(hsh, wqkvh, bq, bk, bv, csh2,
                                             qh, kh, vt2);
  attn_db<<<512, 512, 0, stream>>>(qh, kh, vt2, csh2, aml2, ctxh);
  gemm_o<<<dim3(16, 32), 256, 0, stream>>>(ctxh, woh, bo, hs, xb);
  layernorm<<<BB * LL, 256, 0, stream>>>(xb, lng, lnb, out);
}

// Round 12
// 229.786 us; speedup vs baseline: 1.5164x; 1.0741x over previous
//
#include <hip/hip_runtime.h>
#include <cmath>

#define BB 2
#define LL 2048
#define DD 1024
#define HH 16
#define HDD 64

typedef _Float16 v8h __attribute__((ext_vector_type(8)));
typedef _Float16 v4h __attribute__((ext_vector_type(4)));
typedef _Float16 v2h __attribute__((ext_vector_type(2)));
typedef float v4f __attribute__((ext_vector_type(4)));

#define LOG2E 1.44269504089f
#define NEGB  (-1.442695e9f)      /* -1e9 * log2e */

// async global->LDS, 16B per lane.
#define GLD(gp, lp)                                                        \
  __builtin_amdgcn_global_load_lds(                                        \
      (const __attribute__((address_space(1))) void*)(gp),                 \
      (__attribute__((address_space(3))) void*)(lp), 16, 0, 0)

// ---------------------------------------------------------------------------
// Fused prep: fp32->f16 cvt (hs, Wq/Wk/Wv, Wo) + cos/sin table + am*log2e.
// ---------------------------------------------------------------------------
__global__ __launch_bounds__(256) void prep(
    const float* __restrict__ hs, const float* __restrict__ wq,
    const float* __restrict__ wk, const float* __restrict__ wv,
    const float* __restrict__ wo, const float* __restrict__ phi,
    const float* __restrict__ amk, _Float16* __restrict__ hsh,
    _Float16* __restrict__ wqkvh, _Float16* __restrict__ woh,
    unsigned* __restrict__ csh2, float* __restrict__ aml2)
{
  const int i = blockIdx.x * 256 + threadIdx.x;
  if (i < 2097152) {
    const float* s;
    _Float16* d;
    if (i < 1048576)      { s = hs + (size_t)i * 4;            d = hsh + (size_t)i * 4; }
    else if (i < 1310720) { int j = i - 1048576; s = wq + (size_t)j * 4; d = wqkvh + (size_t)j * 4; }
    else if (i < 1572864) { int j = i - 1310720; s = wk + (size_t)j * 4; d = wqkvh + 1048576 + (size_t)j * 4; }
    else if (i < 1835008) { int j = i - 1572864; s = wv + (size_t)j * 4; d = wqkvh + 2097152 + (size_t)j * 4; }
    else                  { int j = i - 1835008; s = wo + (size_t)j * 4; d = woh + (size_t)j * 4; }
    float4 v = *(const float4*)s;
    v4h o;
    o[0] = (_Float16)v.x; o[1] = (_Float16)v.y;
    o[2] = (_Float16)v.z; o[3] = (_Float16)v.w;
    *(v4h*)d = o;
  } else {
    const int o = i - 2097152;                   // 0..65535 = B*H*L
    if (o < BB * LL) aml2[o] = amk[o] * LOG2E;
    const int l = o & 2047;
    const int h = (o >> 11) & 15;
    const int b = o >> 15;
    const float ph = phi[(b * 2048 + l) * 16 + h];
    v2h cs;
    cs[0] = (_Float16)cosf(ph);
    cs[1] = (_Float16)sinf(ph);
    csh2[o] = __builtin_bit_cast(unsigned, cs);
  }
}

// ---------------------------------------------------------------------------
// m97-style MFMA GEMM core: 128x128 tile, BK=32, 256 thr.
// ---------------------------------------------------------------------------
__device__ __forceinline__ void gemm_loop(
    const _Float16* __restrict__ A, const _Float16* __restrict__ W, const int K,
    const int m0, const int n0, const int tid, const int wave, const int lane,
    _Float16* As, _Float16* Bs, v4f acc[4][4])
{
  const int quad = lane >> 4;
  const int ql = lane & 15;
  const int wm = (wave >> 1) * 64;
  const int wn = (wave & 1) * 64;
  const int srow = tid >> 2;
  const int skof = (tid & 3) * 8;
  const _Float16* Ap = A + (size_t)(m0 + srow) * K + skof;
  const _Float16* Wp = W + (size_t)(n0 + srow) * K + skof;
  const size_t rstep = (size_t)64 * K;
  for (int k0 = 0; k0 < K; k0 += 32) {
    __syncthreads();
    GLD(Ap + k0,         As + tid * 8);
    GLD(Ap + rstep + k0, As + 2048 + tid * 8);
    GLD(Wp + k0,         Bs + tid * 8);
    GLD(Wp + rstep + k0, Bs + 2048 + tid * 8);
    __syncthreads();
    v8h af[4], bf[4];
#pragma unroll
    for (int mt = 0; mt < 4; ++mt)
      af[mt] = *(const v8h*)&As[(wm + mt * 16 + ql) * 32 + quad * 8];
#pragma unroll
    for (int nt = 0; nt < 4; ++nt)
      bf[nt] = *(const v8h*)&Bs[(wn + nt * 16 + ql) * 32 + quad * 8];
#pragma unroll
    for (int mt = 0; mt < 4; ++mt)
#pragma unroll
      for (int nt = 0; nt < 4; ++nt)
        acc[mt][nt] = __builtin_amdgcn_mfma_f32_16x16x32_f16(
            af[mt], bf[nt], acc[mt][nt], 0, 0, 0);
  }
}

// ---------------------------------------------------------------------------
// Fused QKV GEMM (XCD-swizzled). Epilogue:
//   q-band: +bias, rotary (fp32), scale by (1/8)*log2e, single f16 rounding
//   k-band: +bias, rotary (fp32), f16
//   v-band: +bias, written directly in VT2 layout (8B unit [j=key>>2][d])
// ---------------------------------------------------------------------------
__global__ __launch_bounds__(256) void gemm_qkv(
    const _Float16* __restrict__ A, const _Float16* __restrict__ W,
    const float* __restrict__ bqp, const float* __restrict__ bkp,
    const float* __restrict__ bvp, const unsigned* __restrict__ csh2,
    _Float16* __restrict__ qh, _Float16* __restrict__ kh,
    _Float16* __restrict__ vt2)
{
  __shared__ _Float16 As[128 * 32];
  __shared__ _Float16 Bs[128 * 32];
  const int tid = threadIdx.x, lane = tid & 63, wave = tid >> 6;
  const int quad = lane >> 4, ql = lane & 15;
  const int bid0 = blockIdx.y * 24 + blockIdx.x;
  const int bid  = (bid0 & 7) * 96 + (bid0 >> 3);
  const int m0 = (bid / 24) * 128, n0 = (bid % 24) * 128;
  v4f acc[4][4];
#pragma unroll
  for (int mt = 0; mt < 4; ++mt)
#pragma unroll
    for (int nt = 0; nt < 4; ++nt) acc[mt][nt] = (v4f){0.f, 0.f, 0.f, 0.f};
  gemm_loop(A, W, DD, m0, n0, tid, wave, lane, As, Bs, acc);

  const int buf = n0 >> 10;                       // 0=q 1=k 2=v
  const int col0 = (n0 & 1023) + (wave & 1) * 64; // 64-col band == one head
  const int hh = col0 >> 6;
  const int mr0 = m0 + (wave >> 1) * 64;

  if (buf == 2) {
    float bb4[4];
#pragma unroll
    for (int nt = 0; nt < 4; ++nt) bb4[nt] = bvp[col0 + nt * 16 + ql];
#pragma unroll
    for (int mt = 0; mt < 4; ++mt) {
      const int row = mr0 + mt * 16 + quad * 4;   // keys row..row+3
      const int b_ = row >> 11;
      const int l = row & 2047;
      _Float16* dst = vt2 + ((size_t)(b_ * 16 + hh) * 32 + (l >> 6)) * 4096 +
                      ((l >> 2) & 15) * 256;
#pragma unroll
      for (int nt = 0; nt < 4; ++nt) {
        const int d = nt * 16 + ql;
        v4h o4;
#pragma unroll
        for (int r = 0; r < 4; ++r) o4[r] = (_Float16)(acc[mt][nt][r] + bb4[nt]);
        *(v4h*)&dst[d * 4] = o4;
      }
    }
  } else {
    const float scl = (buf == 0) ? 0.125f * LOG2E : 1.0f;
    _Float16* outp = (buf == 0) ? qh : kh;
    const float* bias = (buf == 0) ? bqp : bkp;
    float bb4[4];
#pragma unroll
    for (int nt = 0; nt < 4; ++nt) bb4[nt] = bias[col0 + nt * 16 + ql];
#pragma unroll
    for (int mt = 0; mt < 4; ++mt)
#pragma unroll
      for (int r = 0; r < 4; ++r) {
        const int row = mr0 + mt * 16 + quad * 4 + r;
        const int b_ = row >> 11;
        const int l = row & 2047;
        const v2h c2 = __builtin_bit_cast(
            v2h, csh2[(b_ * 16 + hh) * 2048 + l]);
        const float c = (float)c2[0], s = (float)c2[1];
        _Float16* orow = outp + (size_t)row * DD + col0 + ql;
#pragma unroll
        for (int pp = 0; pp < 2; ++pp) {
          const float a0 = acc[mt][pp][r] + bb4[pp];
          const float a1 = acc[mt][pp + 2][r] + bb4[pp + 2];
          orow[pp * 16]        = (_Float16)((a0 * c - a1 * s) * scl);
          orow[(pp + 2) * 16]  = (_Float16)((a1 * c + a0 * s) * scl);
        }
      }
  }
}

// ---------------------------------------------------------------------------
// O-proj GEMM, 128(M)x64(N) tiles: 512 blocks (2/CU), XCD-swizzled.
// ---------------------------------------------------------------------------
__global__ __launch_bounds__(256) void gemm_o(
    const _Float16* __restrict__ A, const _Float16* __restrict__ W,
    const float* __restrict__ bo, const float* __restrict__ res,
    float* __restrict__ out)
{
  __shared__ _Float16 As[128 * 32];
  __shared__ _Float16 Bs[64 * 32];
  const int tid = threadIdx.x, lane = tid & 63, wave = tid >> 6;
  const int quad = lane >> 4, ql = lane & 15;
  const int bid0 = blockIdx.y * 16 + blockIdx.x;
  const int bid  = (bid0 & 7) * 64 + (bid0 >> 3);
  const int m0 = (bid / 16) * 128, n0 = (bid % 16) * 64;
  v4f acc[4][2];
#pragma unroll
  for (int mt = 0; mt < 4; ++mt)
#pragma unroll
    for (int nt = 0; nt < 2; ++nt) acc[mt][nt] = (v4f){0.f, 0.f, 0.f, 0.f};
  const int wm = (wave >> 1) * 64;
  const int wn = (wave & 1) * 32;
  const int srow = tid >> 2;
  const int skof = (tid & 3) * 8;
  const _Float16* Ap = A + (size_t)(m0 + srow) * DD + skof;
  const _Float16* Wp = W + (size_t)(n0 + srow) * DD + skof;
  const size_t rstep = (size_t)64 * DD;
  for (int k0 = 0; k0 < DD; k0 += 32) {
    __syncthreads();
    GLD(Ap + k0,         As + tid * 8);
    GLD(Ap + rstep + k0, As + 2048 + tid * 8);
    GLD(Wp + k0,         Bs + tid * 8);
    __syncthreads();
    v8h af[4], bf[2];
#pragma unroll
    for (int mt = 0; mt < 4; ++mt)
      af[mt] = *(const v8h*)&As[(wm + mt * 16 + ql) * 32 + quad * 8];
#pragma unroll
    for (int nt = 0; nt < 2; ++nt)
      bf[nt] = *(const v8h*)&Bs[(wn + nt * 16 + ql) * 32 + quad * 8];
#pragma unroll
    for (int mt = 0; mt < 4; ++mt)
#pragma unroll
      for (int nt = 0; nt < 2; ++nt)
        acc[mt][nt] = __builtin_amdgcn_mfma_f32_16x16x32_f16(
            af[mt], bf[nt], acc[mt][nt], 0, 0, 0);
  }
#pragma unroll
  for (int nt = 0; nt < 2; ++nt) {
    const int col = n0 + wn + nt * 16 + ql;
    const float bb = bo[col];
#pragma unroll
    for (int mt = 0; mt < 4; ++mt)
#pragma unroll
      for (int r = 0; r < 4; ++r) {
        const int row = m0 + wm + mt * 16 + quad * 4 + r;
        const size_t ix = (size_t)row * DD + col;
        out[ix] = acc[mt][nt][r] + bb + res[ix];
      }
  }
}

// ---------------------------------------------------------------------------
// Double-buffered LDS flash attention (R7 structure = session best: 32 q/wave,
// two 16-q groups, 2 blocks/CU, setprio around PV, t-loop unrolled x2 for
// compile-time LDS buffer index).
// K-split (R9-R11) refuted: 32q/wave needs ~130+ total regs (88 arch + ~40
// acc in the unified file) > the 128/wave threshold for 4 waves/SIMD -> the
// second block never became resident (occupancy 20.7% = 1 block/CU) and the
// split paid pure overhead. 16q/wave at 4 waves/SIMD already measured worse
// (R0). This config is the measured optimum of the attn design space.
// ---------------------------------------------------------------------------
__global__ __launch_bounds__(256, 2) void attn_db(
    const _Float16* __restrict__ Q, const _Float16* __restrict__ K,
    const _Float16* __restrict__ VT2, const unsigned* __restrict__ csh2,
    const float* __restrict__ aml2, _Float16* __restrict__ ctx)
{
  __shared__ _Float16 Kt[2][4096];   // [buf] 64 rows x 64 dims (16B-swizzled)
  __shared__ _Float16 Vt[2][4096];   // [buf] VT2 tile image (8B units j-major)
  __shared__ float amL[LL];          // am * log2e, whole row: 8 KB

  const int tid  = threadIdx.x;
  const int lane = tid & 63;
  const int wave = tid >> 6;
  const int quad = lane >> 4;
  const int ql   = lane & 15;
  const int bid  = blockIdx.x;       // 512 = 16 qt * 32 bh
  const int bh = bid & 31;           // XCD swizzle: same (b,h) -> same XCD
  const int qt = bid >> 5;
  const int h  = bh & 15;
  const int b  = bh >> 4;
  const int q0w = qt * 128 + wave * 32;   // 32 queries per wave
  const int csb = bh * LL;

  {
    const float* amb = aml2 + b * LL;
    for (int i = tid; i < LL; i += 256) amL[i] = amb[i];
  }

  // Q B-fragments for the two 16-query groups (rotary etc. pre-folded)
  v8h qf0[2], qf1[2];
  v4h bq0, bq1;
  {
    const _Float16* qp = Q + ((size_t)(b * LL + q0w + ql)) * DD + h * 64 + quad * 8;
    qf0[0] = *(const v8h*)qp;
    qf0[1] = *(const v8h*)(qp + 32);
    const v2h c2 = __builtin_bit_cast(v2h, csh2[csb + q0w + ql]);
    v4h t = (v4h){0, 0, 0, 0};
    if (quad == 0) { t[0] = c2[0]; t[1] = c2[1]; }
    bq0 = t;
  }
  {
    const _Float16* qp = Q + ((size_t)(b * LL + q0w + 16 + ql)) * DD + h * 64 + quad * 8;
    qf1[0] = *(const v8h*)qp;
    qf1[1] = *(const v8h*)(qp + 32);
    const v2h c2 = __builtin_bit_cast(v2h, csh2[csb + q0w + 16 + ql]);
    v4h t = (v4h){0, 0, 0, 0};
    if (quad == 0) { t[0] = c2[0]; t[1] = c2[1]; }
    bq1 = t;
  }
  const v4h ones = (v4h){(_Float16)1.f, (_Float16)1.f,
                         (_Float16)1.f, (_Float16)1.f};

  v4f o0[4], o1[4];
#pragma unroll
  for (int nt = 0; nt < 4; ++nt) {
    o0[nt] = (v4f){0.f, 0.f, 0.f, 0.f};
    o1[nt] = (v4f){0.f, 0.f, 0.f, 0.f};
  }
  v4f lacc0 = (v4f){0.f, 0.f, 0.f, 0.f};
  v4f lacc1 = (v4f){0.f, 0.f, 0.f, 0.f};

  const _Float16* Kb   = K + (size_t)(b * LL) * DD + h * 64;     // row stride 1024
  const _Float16* VTb2 = VT2 + (size_t)bh * 131072;              // 32 tiles x 4096
  const unsigned* csk = csh2 + csb;

  const int srow = tid >> 3;                // 0..31 K staging row
  const int kch  = (tid & 7) ^ (srow & 7);  // swizzled source 16B chunk (K only)

  // prologue: tile 0 -> buf 0; csk for tile 0 -> registers
  {
    const size_t kg = (size_t)srow * 1024 + kch * 8;
    GLD(Kb + kg,             &Kt[0][tid * 8]);
    GLD(Kb + kg + 32 * 1024, &Kt[0][2048 + tid * 8]);
    GLD(VTb2 + tid * 8,          &Vt[0][tid * 8]);
    GLD(VTb2 + 2048 + tid * 8,   &Vt[0][2048 + tid * 8]);
  }
  unsigned cs_cur[4], cs_nxt[4];
#pragma unroll
  for (int c = 0; c < 4; ++c) cs_cur[c] = csk[c * 16 + ql];
  __syncthreads();

  for (int tt = 0; tt < 16; ++tt) {
#pragma unroll
    for (int u = 0; u < 2; ++u) {          // u == compile-time buffer index
      const int t = tt * 2 + u;
      const int k0 = t * 64;
      if (t < 31) {
        const int k1 = k0 + 64;
        const size_t kg = (size_t)(k1 + srow) * 1024 + kch * 8;
        GLD(Kb + kg,             &Kt[u ^ 1][tid * 8]);
        GLD(Kb + kg + 32 * 1024, &Kt[u ^ 1][2048 + tid * 8]);
        const _Float16* vsrc = VTb2 + (size_t)(t + 1) * 4096;
        GLD(vsrc + tid * 8,        &Vt[u ^ 1][tid * 8]);
        GLD(vsrc + 2048 + tid * 8, &Vt[u ^ 1][2048 + tid * 8]);
#pragma unroll
        for (int c = 0; c < 4; ++c) cs_nxt[c] = csk[k1 + c * 16 + ql];
      }
      const _Float16* KtB = Kt[u];
      const _Float16* VtB = Vt[u];

      // --- S^T (log2 domain) + mask-dot MFMA, q-groups sharing K frags ---
      v4f st0[4], st1[4], dd0[4], dd1[4];
#pragma unroll
      for (int c = 0; c < 4; ++c) {
        const int row = c * 16 + ql;
        const int sw = row & 7;
        v8h a0 = *(const v8h*)&KtB[row * 64 + ((quad ^ sw) << 3)];
        v8h a1 = *(const v8h*)&KtB[row * 64 + (((quad + 4) ^ sw) << 3)];
        v4f z0 = (v4f){0.f, 0.f, 0.f, 0.f};
        z0 = __builtin_amdgcn_mfma_f32_16x16x32_f16(a0, qf0[0], z0, 0, 0, 0);
        z0 = __builtin_amdgcn_mfma_f32_16x16x32_f16(a1, qf0[1], z0, 0, 0, 0);
        st0[c] = z0;
        v4f z1 = (v4f){0.f, 0.f, 0.f, 0.f};
        z1 = __builtin_amdgcn_mfma_f32_16x16x32_f16(a0, qf1[0], z1, 0, 0, 0);
        z1 = __builtin_amdgcn_mfma_f32_16x16x32_f16(a1, qf1[1], z1, 0, 0, 0);
        st1[c] = z1;
        const v2h c2 = __builtin_bit_cast(v2h, cs_cur[c]);
        v4h a = (v4h){0, 0, 0, 0};
        if (quad == 0) { a[0] = c2[0]; a[1] = c2[1]; }
        dd0[c] = __builtin_amdgcn_mfma_f32_16x16x16f16(
            a, bq0, (v4f){0.f, 0.f, 0.f, 0.f}, 0, 0, 0);
        dd1[c] = __builtin_amdgcn_mfma_f32_16x16x16f16(
            a, bq1, (v4f){0.f, 0.f, 0.f, 0.f}, 0, 0, 0);
      }

      // --- mask + P = exp2(score + am): cmp + cndmask + add + exp2 ---
      v4h pf0[4], pf1[4];
#pragma unroll
      for (int c = 0; c < 4; ++c) {
        const v4f am4 = *(const v4f*)&amL[k0 + c * 16 + quad * 4];
        float p0[4], p1[4];
#pragma unroll
        for (int r = 0; r < 4; ++r) {
          p0[r] = __builtin_amdgcn_exp2f(
              ((dd0[c][r] < -0.7f) ? NEGB : st0[c][r]) + am4[r]);
          p1[r] = __builtin_amdgcn_exp2f(
              ((dd1[c][r] < -0.7f) ? NEGB : st1[c][r]) + am4[r]);
        }
        const unsigned a01 = __builtin_bit_cast(
            unsigned, __builtin_amdgcn_cvt_pkrtz(p0[0], p0[1]));
        const unsigned a23 = __builtin_bit_cast(
            unsigned, __builtin_amdgcn_cvt_pkrtz(p0[2], p0[3]));
        pf0[c] = __builtin_bit_cast(v4h, make_uint2(a01, a23));
        const unsigned b01 = __builtin_bit_cast(
            unsigned, __builtin_amdgcn_cvt_pkrtz(p1[0], p1[1]));
        const unsigned b23 = __builtin_bit_cast(
            unsigned, __builtin_amdgcn_cvt_pkrtz(p1[2], p1[3]));
        pf1[c] = __builtin_bit_cast(v4h, make_uint2(b01, b23));
      }

      // --- PV + row-sum, V frags shared by both q-groups (pure MFMA) ---
      __builtin_amdgcn_s_setprio(1);
#pragma unroll
      for (int c = 0; c < 4; ++c) {
        lacc0 = __builtin_amdgcn_mfma_f32_16x16x16f16(pf0[c], ones, lacc0, 0, 0, 0);
        lacc1 = __builtin_amdgcn_mfma_f32_16x16x16f16(pf1[c], ones, lacc1, 0, 0, 0);
#pragma unroll
        for (int nt = 0; nt < 4; ++nt) {
          const v4h vv = *(const v4h*)&VtB[((c * 4 + quad) * 64 +
                                            nt * 16 + ql) * 4];
          o0[nt] = __builtin_amdgcn_mfma_f32_16x16x16f16(pf0[c], vv, o0[nt], 0, 0, 0);
          o1[nt] = __builtin_amdgcn_mfma_f32_16x16x16f16(pf1[c], vv, o1[nt], 0, 0, 0);
        }
      }
      __builtin_amdgcn_s_setprio(0);
#pragma unroll
      for (int c = 0; c < 4; ++c) cs_cur[c] = cs_nxt[c];
      __syncthreads();
    }
  }

  // epilogue: lacc is already in O's row layout (query = g*16 + quad*4 + r)
#pragma unroll
  for (int g = 0; g < 2; ++g) {
    const v4f* op = g ? o1 : o0;
    const v4f la = g ? lacc1 : lacc0;
#pragma unroll
    for (int r = 0; r < 4; ++r) {
      const int q = q0w + g * 16 + quad * 4 + r;
      const float lr = la[r];
      const size_t ob = (size_t)(b * LL + q) * DD + h * 64 + ql;
      if (lr <= 0.f) {  // all-masked fallback (never taken with am=0)
        const _Float16* vsrc = VTb2 + (q >> 6) * 4096 +
                               ((q >> 2) & 15) * 256 + (q & 3);
#pragma unroll
        for (int nt = 0; nt < 4; ++nt)
          ctx[ob + nt * 16] = vsrc[(nt * 16 + ql) * 4];
      } else {
        const float inv = 1.f / lr;
        ctx[ob + 0]  = (_Float16)(op[0][r] * inv);
        ctx[ob + 16] = (_Float16)(op[1][r] * inv);
        ctx[ob + 32] = (_Float16)(op[2][r] * inv);
        ctx[ob + 48] = (_Float16)(op[3][r] * inv);
      }
    }
  }
}

// ---------------------------------------------------------------------------
// LayerNorm over D=1024, float4 loads/stores
// ---------------------------------------------------------------------------
__global__ __launch_bounds__(256) void layernorm(
    const float* __restrict__ x, const float* __restrict__ g,
    const float* __restrict__ bta, float* __restrict__ out)
{
  __shared__ float red[8];
  const int row = blockIdx.x;
  const int tid = threadIdx.x;
  const float4 vv = ((const float4*)(x + (size_t)row * DD))[tid];
  float lsum = vv.x + vv.y + vv.z + vv.w;
  float lsq  = vv.x * vv.x + vv.y * vv.y + vv.z * vv.z + vv.w * vv.w;
#pragma unroll
  for (int off = 32; off > 0; off >>= 1) {
    lsum += __shfl_down(lsum, off, 64);
    lsq  += __shfl_down(lsq,  off, 64);
  }
  const int wid = tid >> 6;
  if ((tid & 63) == 0) { red[wid] = lsum; red[wid + 4] = lsq; }
  __syncthreads();
  const float tsum = red[0] + red[1] + red[2] + red[3];
  const float tsq  = red[4] + red[5] + red[6] + red[7];
  const float mean = tsum * (1.f / DD);
  const float var  = tsq * (1.f / DD) - mean * mean;
  const float inv  = rsqrtf(var + 1e-12f);
  const float4 gg = ((const float4*)g)[tid];
  const float4 bb = ((const float4*)bta)[tid];
  float4 oo;
  oo.x = (vv.x - mean) * inv * gg.x + bb.x;
  oo.y = (vv.y - mean) * inv * gg.y + bb.y;
  oo.z = (vv.z - mean) * inv * gg.z + bb.z;
  oo.w = (vv.w - mean) * inv * gg.w + bb.w;
  ((float4*)(out + (size_t)row * DD))[tid] = oo;
}

// ---------------------------------------------------------------------------
extern "C" void kernel_launch(void* const* d_in, const int* in_sizes, int n_in,
                              void* d_out, int out_size, void* d_ws, size_t ws_size,
                              hipStream_t stream)
{
  const float* hs  = (const float*)d_in[0];
  const float* amk = (const float*)d_in[1];
  const float* phi = (const float*)d_in[2];
  const float* Wq  = (const float*)d_in[3];
  const float* bq  = (const float*)d_in[4];
  const float* Wk  = (const float*)d_in[5];
  const float* bk  = (const float*)d_in[6];
  const float* Wv  = (const float*)d_in[7];
  const float* bv  = (const float*)d_in[8];
  const float* Wo  = (const float*)d_in[9];
  const float* bo  = (const float*)d_in[10];
  const float* lng = (const float*)d_in[11];
  const float* lnb = (const float*)d_in[12];
  float* out = (float*)d_out;

  const size_t SZ = (size_t)BB * LL * DD;   // 4 M elements
  _Float16* hsh   = (_Float16*)d_ws;
  _Float16* qh    = hsh + SZ;
  _Float16* kh    = qh + SZ;
  _Float16* vt2   = kh + SZ;                // 4 M (V pre-tiled VT2)
  _Float16* ctxh  = vt2 + SZ;
  _Float16* wqkvh = ctxh + SZ;              // 3 M
  _Float16* woh   = wqkvh + 3 * (size_t)DD * DD;  // 1 M
  float* xb    = (float*)(woh + (size_t)DD * DD);
  unsigned* csh2 = (unsigned*)(xb + SZ);    // B*H*L packed {cos,sin} f16
  float* aml2 = (float*)(csh2 + (size_t)BB * HH * LL);  // B*L am*log2e

  prep<<<8448, 256, 0, stream>>>(hs, Wq, Wk, Wv, Wo, phi, amk,
                                 hsh, wqkvh, woh, csh2, aml2);
  gemm_qkv<<<dim3(24, 32), 256, 0, stream>>>(hsh, wqkvh, bq, bk, bv, csh2,
                                             qh, kh, vt2);
  attn_db<<<512, 256, 0, stream>>>(qh, kh, vt2, csh2, aml2, ctxh);
  gemm_o<<<dim3(16, 32), 256, 0, stream>>>(ctxh, woh, bo, hs, xb);
  layernorm<<<BB * LL, 256, 0, stream>>>(xb, lng, lnb, out);
}